// Round 13
// baseline (1274.075 us; speedup 1.0000x reference)
//
#include <hip/hip_runtime.h>
#include <math.h>

// ExperimentalModel_1752346656819: 4-stage dynamic-conv decoder, fp32 end-to-end.
// R12: conv3_fused LDS union halved via 2-channel phases (convr 4x, convm 4x)
// -> 15.5KB/block -> 8 blocks/CU (wave cap, 100% occupancy potential) vs 5.
// Compute indexing and FP order identical to R11; only staging phases changed.

#define BLK 256
#define EF 2.7182818284590452f

struct W1Args { const float* M[12]; float* out[12]; };
struct W2Args { const float* W[4]; const float* u[4]; const float* v[4]; float* out[4]; };

__device__ __forceinline__ float dln_one(float y, float m){
  float a = fabsf(y) - m;
  float v = __logf(__logf(a + EF) + 0.01f);
  return (y > 0.0f) ? v : -v;
}

__global__ void gather_ctx_kernel(const int* __restrict__ ids,
                                  const float* __restrict__ cache,
                                  float* __restrict__ ctx){
  int e = blockIdx.x*blockDim.x + threadIdx.x;
  if (e < 64*32){
    int b = e >> 5, l = e & 31;
    ctx[e] = cache[(size_t)ids[b]*32 + l];
  }
}

__global__ void gather_x_kernel(const int* __restrict__ ids,
                                const float* __restrict__ lat,
                                float* __restrict__ X, int b0, int nb){
  int total = nb*2048;
  int e = blockIdx.x*blockDim.x + threadIdx.x;
  if (e < total){
    int bl = e >> 11;
    int r  = e & 2047;
    X[e] = lat[(size_t)ids[b0+bl]*2048 + r];
  }
}

__global__ void w1_kernel(const float* __restrict__ ctx, W1Args args){
  const int S[12] = {4,4,4,4,4,4,4,4,4,1,1,1};
  const int K[12] = {128,1152,128,2048,128,3200,8,8,8,48,128,3};
  int tid = blockIdx.x*blockDim.x + threadIdx.x;
  int nth = gridDim.x*blockDim.x;
  for (int seg = 0; seg < 12; ++seg){
    const float* M = args.M[seg];
    float* out = args.out[seg];
    int Ks = K[seg];
    int total = S[seg]*64*Ks;
    for (int e = tid; e < total; e += nth){
      int k = e % Ks;
      int b = (e / Ks) % 64;
      int s = e / (Ks*64);
      const float* Ms = M + (size_t)s*32*Ks + k;
      const float* cb = ctx + b*32;
      float acc = 0.f;
      #pragma unroll
      for (int l = 0; l < 32; ++l) acc += cb[l]*Ms[(size_t)l*Ks];
      out[e] = acc;
    }
  }
}

// Dynamic weights. Segs 0-2 TRANSPOSED to [s][b][i][p][q][o]; seg 3 [b][o][i].
__global__ void w2_kernel(W2Args args){
  const int S[4] = {4,4,4,1};
  const int O[4] = {8,8,8,3};
  const int K[4] = {72,128,200,8};
  const int KH[4] = {3,4,5,1};
  int tid = blockIdx.x*blockDim.x + threadIdx.x;
  int nth = gridDim.x*blockDim.x;
  for (int seg = 0; seg < 4; ++seg){
    int Os = O[seg], Ks = K[seg];
    int kh = KH[seg], kk = kh*kh;
    int total = S[seg]*64*Os*Ks;
    const float* Wt = args.W[seg];
    const float* u = args.u[seg];
    const float* v = args.v[seg];
    float* out = args.out[seg];
    for (int e = tid; e < total; e += nth){
      int k = e % Ks;
      int o = (e/Ks) % Os;
      int b = (e/(Ks*Os)) % 64;
      int s = e/(Ks*Os*64);
      const float* us = u + (size_t)(s*64+b)*16*Os;
      const float* vs = v + (size_t)(s*64+b)*16*Ks;
      float mod = 0.f;
      #pragma unroll
      for (int r = 0; r < 16; ++r) mod += us[r*Os+o]*vs[r*Ks+k];
      float val = Wt[(size_t)(s*Os+o)*Ks + k] * (1.0f + mod + 1e-3f);
      size_t dst;
      if (seg < 3){
        int i = k / kk, r2 = k - i*kk, p = r2 / kh, q = r2 - p*kh;
        dst = (size_t)(s*64+b)*(8*Ks) + (size_t)(((i*kh+p)*kh+q)*8 + o);
      } else {
        dst = (size_t)b*24 + o*8 + k;
      }
      out[dst] = val;
    }
  }
}

__global__ void init_min_kernel(unsigned* __restrict__ mn, int n){
  int e = blockIdx.x*blockDim.x + threadIdx.x;
  if (e < n) mn[e] = 0x7F800000u;   // +inf
}

// Fused per-stage conv kernel: blocks [0,gR) = 3x3 conv; [gR,gR+gT) = 4x4
// stride-2 transposed conv; [gR+gT, ...) = 5x5 conv on bilinear-up(log).
// LDS union: 3880 floats (convm: 2880 tile + 1000 lbuf) = 15.5 KB.
__global__ void __launch_bounds__(BLK) conv3_fused(
    const float* __restrict__ X,
    const float* __restrict__ wr, const float* __restrict__ br,
    const float* __restrict__ wt, const float* __restrict__ bt,
    const float* __restrict__ wm, const float* __restrict__ bm,
    float* __restrict__ D, float* __restrict__ T, float* __restrict__ M,
    unsigned* __restrict__ mn, int maps, int H, int b0, int s,
    int tprR, int tprO, int gR, int gT){
  __shared__ __align__(16) float smem[3880];
  const int bid = blockIdx.x;

  if (bid < gR){
    // ------------- 3x3 conv (pad 1), FOUR phases of 2 input ch -------------
    float* tile = smem;                       // 2*34*36 = 2448
    const int tiles = tprR*tprR;
    const int bl = bid / tiles;
    const int t  = bid - bl*tiles;
    const int Y0 = (t/tprR)*32, X0 = (t - (t/tprR)*tprR)*32;
    const int bg = b0 + bl;
    const float* wb = wr + (size_t)(s*64+bg)*576;
    const float* bb = br + (s*64+bg)*8;
    const int HW = H*H;
    const float* xb = X + (size_t)bl*8*HW;
    const int tx = threadIdx.x & 7, ty = threadIdx.x >> 3;
    const bool act = (Y0+ty < H) && (X0+4*tx < H);  // only false when H==16
    float a[8][4];
    #pragma unroll
    for (int o = 0; o < 8; ++o){
      float b = bb[o];
      a[o][0]=b; a[o][1]=b; a[o][2]=b; a[o][3]=b;
    }
    #pragma unroll 1
    for (int ph = 0; ph < 4; ++ph){
      __syncthreads();
      {
        float vb[10];
        #pragma unroll
        for (int k = 0; k < 10; ++k){
          int e = threadIdx.x + k*BLK;
          float v = 0.f;
          if (e < 2448){
            int cc = e % 36; int rr = (e/36) % 34; int c2 = e/(36*34);
            int gy = Y0 - 1 + rr, gx = X0 - 1 + cc;
            if (cc < 34 && (unsigned)gy < (unsigned)H && (unsigned)gx < (unsigned)H)
              v = xb[(size_t)(ph*2 + c2)*HW + gy*H + gx];
          }
          vb[k] = v;
        }
        #pragma unroll
        for (int k = 0; k < 10; ++k){
          int e = threadIdx.x + k*BLK;
          if (e < 2448) tile[e] = vb[k];
        }
      }
      __syncthreads();
      #pragma unroll 1
      for (int i = 0; i < 2; ++i){
        const float* tch = tile + i*1224;
        const int ig = ph*2 + i;
        #pragma unroll
        for (int p = 0; p < 3; ++p){
          const float* row = tch + (ty+p)*36 + 4*tx;
          float4 c0 = *(const float4*)row;
          float4 c1 = *(const float4*)(row+4);
          float c[8] = {c0.x,c0.y,c0.z,c0.w,c1.x,c1.y,c1.z,c1.w};
          const float* wip = wb + (ig*3+p)*24;
          float w[24];
          #pragma unroll
          for (int k = 0; k < 24; ++k) w[k] = wip[k];
          #pragma unroll
          for (int q = 0; q < 3; ++q){
            #pragma unroll
            for (int o = 0; o < 8; ++o){
              float wq = w[q*8+o];
              a[o][0] += wq*c[q];   a[o][1] += wq*c[q+1];
              a[o][2] += wq*c[q+2]; a[o][3] += wq*c[q+3];
            }
          }
        }
      }
    }
    float lm[8];
    #pragma unroll
    for (int o = 0; o < 8; ++o){
      float v = act ? fminf(fminf(fabsf(a[o][0]),fabsf(a[o][1])),
                            fminf(fabsf(a[o][2]),fabsf(a[o][3]))) : 3.4e38f;
      #pragma unroll
      for (int off = 32; off > 0; off >>= 1) v = fminf(v, __shfl_xor(v, off));
      lm[o] = v;
      if (act){
        *(float4*)(D + ((size_t)(bl*8+o))*HW + (Y0+ty)*H + X0 + 4*tx) =
            make_float4(a[o][0],a[o][1],a[o][2],a[o][3]);
      }
    }
    if ((threadIdx.x & 63) == 0){
      #pragma unroll
      for (int o = 0; o < 8; ++o) atomicMin(mn + bl*8 + o, __float_as_uint(lm[o]));
    }
    return;
  }

  if (bid < gR + gT){
    // ------- 4x4 stride-2 transposed conv of (-x) (pad 1), 32x32 out tile -------
    float* tile = smem;                       // 8*18*20 = 2880
    const int idx = bid - gR;
    const int tiles = tprO*tprO;
    const int bl = idx / tiles;
    const int t  = idx - bl*tiles;
    const int Y0 = (t/tprO)*32, X0 = (t - (t/tprO)*tprO)*32;  // output coords
    const int bg = b0 + bl;
    const float* wb = wt + (size_t)(s*64+bg)*1024;
    const float* bb = bt + (s*64+bg)*8;
    const int Ho = 2*H, HWo = Ho*Ho, HW = H*H;
    const float* xb = X + (size_t)bl*8*HW;
    const int ry0 = Y0/2 - 1, rx0 = X0/2 - 1;
    {
      float vb[12];
      #pragma unroll
      for (int k = 0; k < 12; ++k){
        int e = threadIdx.x + k*BLK;
        float v = 0.f;
        if (e < 2880){
          int cc = e % 20; int rr = (e/20) % 18; int ch = e/(20*18);
          int gy = ry0 + rr, gx = rx0 + cc;
          if (cc < 18 && (unsigned)gy < (unsigned)H && (unsigned)gx < (unsigned)H)
            v = xb[(size_t)ch*HW + gy*H + gx];
        }
        vb[k] = v;
      }
      #pragma unroll
      for (int k = 0; k < 12; ++k){
        int e = threadIdx.x + k*BLK;
        if (e < 2880) tile[e] = vb[k];
      }
    }
    __syncthreads();
    const int tx = threadIdx.x & 7;
    const int ty2 = threadIdx.x >> 3;
    const int row = (ty2 < 16) ? 2*ty2 : 2*(ty2-16)+1;   // wave-parity-uniform
    const int yodd = __builtin_amdgcn_readfirstlane(row & 1);
    const int half = row >> 1;
    const int pA = yodd ? 0 : 1, rA = yodd ? half+2 : half+1;
    const int pB = yodd ? 2 : 3, rB = yodd ? half+1 : half;
    float a[8][4];
    #pragma unroll
    for (int o = 0; o < 8; ++o){
      float b = bb[o];
      a[o][0]=b; a[o][1]=b; a[o][2]=b; a[o][3]=b;
    }
    #pragma unroll 1
    for (int i = 0; i < 8; ++i){
      #pragma unroll
      for (int rt = 0; rt < 2; ++rt){
        const int p = rt ? pB : pA;
        const int ri = rt ? rB : rA;
        const float* rowp = tile + i*360 + ri*20 + 2*tx;
        float e0 = rowp[0], e1 = rowp[1], e2 = rowp[2], e3 = rowp[3];
        const float* wip = wb + (i*4+p)*32;   // [q][o], uniform
        float w[32];
        #pragma unroll
        for (int k = 0; k < 32; ++k) w[k] = wip[k];
        #pragma unroll
        for (int o = 0; o < 8; ++o){
          float w1 = w[8+o];  a[o][0] -= w1*e1; a[o][2] -= w1*e2;  // x even, q=1
          float w3 = w[24+o]; a[o][0] -= w3*e0; a[o][2] -= w3*e1;  // x even, q=3
          float w0 = w[o];    a[o][1] -= w0*e2; a[o][3] -= w0*e3;  // x odd,  q=0
          float w2 = w[16+o]; a[o][1] -= w2*e1; a[o][3] -= w2*e2;  // x odd,  q=2
        }
      }
    }
    float lm[8];
    #pragma unroll
    for (int o = 0; o < 8; ++o){
      float v = fminf(fminf(fabsf(a[o][0]),fabsf(a[o][1])),
                      fminf(fabsf(a[o][2]),fabsf(a[o][3])));
      #pragma unroll
      for (int off = 32; off > 0; off >>= 1) v = fminf(v, __shfl_xor(v, off));
      lm[o] = v;
      *(float4*)(T + ((size_t)(bl*8+o))*HWo + (Y0+row)*Ho + X0 + 4*tx) =
          make_float4(a[o][0],a[o][1],a[o][2],a[o][3]);
    }
    if ((threadIdx.x & 63) == 0){
      #pragma unroll
      for (int o = 0; o < 8; ++o)
        atomicMin(mn + maps + bl*8 + o, __float_as_uint(lm[o]));
    }
    return;
  }

  // --- 5x5 conv (pad 2) on bilinear-up(log(|X|+1)); FOUR phases of 2 ch ---
  {
    float* tile = smem;                       // 2*36*40 = 2880
    float* lbuf = smem + 2880;                // 2*20*25 = 1000
    const int idx = bid - gR - gT;
    const int tiles = tprO*tprO;
    const int bl = idx / tiles;
    const int t  = idx - bl*tiles;
    const int Y0 = (t/tprO)*32, X0 = (t - (t/tprO)*tprO)*32;
    const int bg = b0 + bl;
    const float* wb = wm + (size_t)(s*64+bg)*1600;
    const float* bb = bm + (s*64+bg)*8;
    const int Hi = 2*H;
    const int Hq = H, HWq = Hq*Hq;
    const int HW = Hi*Hi;
    const float* xb = X + (size_t)bl*8*HWq;
    const int LY0 = ((Y0-2)>>1) - 1;
    const int LX0 = ((X0-2)>>1) - 1;
    const int tx = threadIdx.x & 7, ty = threadIdx.x >> 3;
    float a[8][4];
    #pragma unroll
    for (int o = 0; o < 8; ++o){
      float b = bb[o];
      a[o][0]=b; a[o][1]=b; a[o][2]=b; a[o][3]=b;
    }
    #pragma unroll 1
    for (int ph = 0; ph < 4; ++ph){
      __syncthreads();
      // stage quarter-res log halo: 2 ch x 20 x 25(stride, 22 used) = 1000
      #pragma unroll
      for (int k = 0; k < 4; ++k){
        int e = threadIdx.x + k*BLK;
        if (e < 1000){
          int c2 = e/500; int r2 = e - c2*500; int rr = r2/25; int cc = r2 - rr*25;
          int ly = LY0 + rr, lx = LX0 + cc;
          float v = 0.f;
          if (cc < 22 && (unsigned)ly < (unsigned)Hq && (unsigned)lx < (unsigned)Hq){
            float xv = xb[(size_t)(ph*2 + c2)*HWq + ly*Hq + lx];
            v = __logf(fabsf(xv) + 1.0f);
          }
          lbuf[e] = v;
        }
      }
      __syncthreads();
      // expand 2x bilinear (half-pixel, edge clamp) into 36x40 halo tile
      #pragma unroll 1
      for (int e = threadIdx.x; e < 2880; e += BLK){
        int c2 = e/1440; int r2 = e - c2*1440; int rr = r2/40; int cc = r2 - rr*40;
        int gy = Y0 - 2 + rr, gx = X0 - 2 + cc;
        float f = 0.f;
        if (cc < 36 && (unsigned)gy < (unsigned)Hi && (unsigned)gx < (unsigned)Hi){
          int jy = gy >> 1;
          int ny = (gy & 1) ? ((jy+1 < Hq) ? jy+1 : Hq-1) : ((jy > 0) ? jy-1 : 0);
          int jx = gx >> 1;
          int nx = (gx & 1) ? ((jx+1 < Hq) ? jx+1 : Hq-1) : ((jx > 0) ? jx-1 : 0);
          const float* lb = lbuf + c2*500;
          float f00 = lb[(jy-LY0)*25 + (jx-LX0)];
          float f01 = lb[(jy-LY0)*25 + (nx-LX0)];
          float f10 = lb[(ny-LY0)*25 + (jx-LX0)];
          float f11 = lb[(ny-LY0)*25 + (nx-LX0)];
          f = 0.5625f*f00 + 0.1875f*(f01 + f10) + 0.0625f*f11;
        }
        tile[e] = f;
      }
      __syncthreads();
      #pragma unroll 1
      for (int i = 0; i < 2; ++i){
        const float* tch = tile + i*1440;
        const int ig = ph*2 + i;
        #pragma unroll
        for (int p = 0; p < 5; ++p){
          const float* row = tch + (ty+p)*40 + 4*tx;
          float4 c0 = *(const float4*)row;
          float4 c1 = *(const float4*)(row+4);
          float c[8] = {c0.x,c0.y,c0.z,c0.w,c1.x,c1.y,c1.z,c1.w};
          const float* wip = wb + (ig*5+p)*40;   // [q][o], uniform
          float w[40];
          #pragma unroll
          for (int k = 0; k < 40; ++k) w[k] = wip[k];
          #pragma unroll
          for (int q = 0; q < 5; ++q){
            #pragma unroll
            for (int o = 0; o < 8; ++o){
              float wq = w[q*8+o];
              a[o][0] += wq*c[q];   a[o][1] += wq*c[q+1];
              a[o][2] += wq*c[q+2]; a[o][3] += wq*c[q+3];
            }
          }
        }
      }
    }
    float lm[8];
    #pragma unroll
    for (int o = 0; o < 8; ++o){
      float v = fminf(fminf(fabsf(a[o][0]),fabsf(a[o][1])),
                      fminf(fabsf(a[o][2]),fabsf(a[o][3])));
      #pragma unroll
      for (int off = 32; off > 0; off >>= 1) v = fminf(v, __shfl_xor(v, off));
      lm[o] = v;
      *(float4*)(M + ((size_t)(bl*8+o))*HW + (Y0+ty)*Hi + X0 + 4*tx) =
          make_float4(a[o][0],a[o][1],a[o][2],a[o][3]);
    }
    if ((threadIdx.x & 63) == 0){
      #pragma unroll
      for (int o = 0; o < 8; ++o)
        atomicMin(mn + 2*maps + bl*8 + o, __float_as_uint(lm[o]));
    }
  }
}

// s<3: next_x = (dln(Dr)[nearest-up] + dln(Dt)) * dln(Dm), into X. Quarter-px threads.
__global__ void combine_kernel(const float* __restrict__ dr, const float* __restrict__ dt,
                               const float* __restrict__ dm,
                               const unsigned* __restrict__ mn, int maps,
                               float* __restrict__ outx, int H, int total){
  int Ho = 2*H, HWo = Ho*Ho, HW = H*H;
  for (int e = blockIdx.x*blockDim.x + threadIdx.x; e < total; e += gridDim.x*blockDim.x){
    int m = e / HW;
    int qpx = e - m*HW;
    int qy = qpx / H, qx = qpx - qy*H;
    float mr = __uint_as_float(mn[m]);
    float mt = __uint_as_float(mn[maps + m]);
    float mm = __uint_as_float(mn[2*maps + m]);
    float r = dln_one(dr[(size_t)m*HW + qpx], mr);
    #pragma unroll
    for (int dy = 0; dy < 2; ++dy){
      size_t base = (size_t)m*HWo + (2*qy+dy)*Ho + 2*qx;
      float2 tv = *(const float2*)(dt + base);
      float2 mv = *(const float2*)(dm + base);
      float2 ov;
      ov.x = (r + dln_one(tv.x, mt)) * dln_one(mv.x, mm);
      ov.y = (r + dln_one(tv.y, mt)) * dln_one(mv.y, mm);
      *(float2*)(outx + base) = ov;
    }
  }
}

// s==3: combine + final dynamic 1x1 conv (8->3 ch) fused, writes d_out.
__global__ void combineF_kernel(const float* __restrict__ dr, const float* __restrict__ dt,
                                const float* __restrict__ dm,
                                const unsigned* __restrict__ mn, int maps,
                                const float* __restrict__ wo, const float* __restrict__ bo,
                                float* __restrict__ out, int b0, int total){
  for (int e = blockIdx.x*blockDim.x + threadIdx.x; e < total; e += gridDim.x*blockDim.x){
    int bl = e >> 14;
    int qpx = e & 16383;
    int qy = qpx >> 7, qx = qpx & 127;
    int bg = b0 + bl;
    float r[8], mtv[8], mmv[8];
    #pragma unroll
    for (int o = 0; o < 8; ++o){
      int m = bl*8 + o;
      float mr = __uint_as_float(mn[m]);
      mtv[o] = __uint_as_float(mn[maps + m]);
      mmv[o] = __uint_as_float(mn[2*maps + m]);
      r[o] = dln_one(dr[(size_t)m*16384 + qpx], mr);
    }
    #pragma unroll
    for (int dy = 0; dy < 2; ++dy){
      int y = 2*qy + dy, xx = 2*qx;
      float2 acc[3];
      #pragma unroll
      for (int of = 0; of < 3; ++of){
        float b = bo[bg*3 + of];
        acc[of].x = b; acc[of].y = b;
      }
      #pragma unroll
      for (int o = 0; o < 8; ++o){
        size_t base = (size_t)(bl*8+o)*65536 + y*256 + xx;
        float2 tv = *(const float2*)(dt + base);
        float2 mv = *(const float2*)(dm + base);
        float vx = (r[o] + dln_one(tv.x, mtv[o])) * dln_one(mv.x, mmv[o]);
        float vy = (r[o] + dln_one(tv.y, mtv[o])) * dln_one(mv.y, mmv[o]);
        #pragma unroll
        for (int of = 0; of < 3; ++of){
          float w = wo[bg*24 + of*8 + o];
          acc[of].x += w*vx; acc[of].y += w*vy;
        }
      }
      #pragma unroll
      for (int of = 0; of < 3; ++of){
        *(float2*)(out + ((size_t)(bg*3 + of))*65536 + y*256 + xx) = acc[of];
      }
    }
  }
}

static inline int grid_for(long long total){
  long long g = (total + BLK - 1) / BLK;
  if (g > 16384) g = 16384;
  if (g < 1) g = 1;
  return (int)g;
}

extern "C" void kernel_launch(void* const* d_in, const int* in_sizes, int n_in,
                              void* d_out, int out_size, void* d_ws, size_t ws_size,
                              hipStream_t stream){
  (void)in_sizes; (void)n_in; (void)out_size;
  const int*   ids   = (const int*)d_in[0];
  const float* cache = (const float*)d_in[1];
  const float* lat   = (const float*)d_in[2];
  const float* Wr = (const float*)d_in[3];
  const float* Ur = (const float*)d_in[4];
  const float* Vr = (const float*)d_in[5];
  const float* Br = (const float*)d_in[6];
  const float* Wt = (const float*)d_in[7];
  const float* Ut = (const float*)d_in[8];
  const float* Vt = (const float*)d_in[9];
  const float* Bt = (const float*)d_in[10];
  const float* Wm = (const float*)d_in[11];
  const float* Um = (const float*)d_in[12];
  const float* Vm = (const float*)d_in[13];
  const float* Bm = (const float*)d_in[14];
  const float* Wo = (const float*)d_in[15];
  const float* Uo = (const float*)d_in[16];
  const float* Vo = (const float*)d_in[17];
  const float* Bo = (const float*)d_in[18];
  float* out = (float*)d_out;
  float* ws  = (float*)d_ws;

  size_t off = 0;
  auto alloc = [&](size_t n){ size_t o = off; off += n; return o; };
  size_t o_ctx = alloc(2048);
  size_t o_ur = alloc(4*64*128),  o_vr = alloc(4*64*1152);
  size_t o_ut = alloc(4*64*128),  o_vt = alloc(4*64*2048);
  size_t o_um = alloc(4*64*128),  o_vm = alloc(4*64*3200);
  size_t o_br = alloc(4*64*8), o_bt = alloc(4*64*8), o_bm = alloc(4*64*8);
  size_t o_uo = alloc(64*48), o_vo = alloc(64*128), o_bo = alloc(64*3);
  size_t o_wr = alloc(4*64*8*72), o_wt = alloc(4*64*8*128), o_wm = alloc(4*64*8*200);
  size_t o_wo = alloc(64*24);
  size_t o_mn = alloc(4*3*512);          // [stage][3][maps]
  size_t small_end = off;

  // per sample: X (8*128^2) + D (8*128^2) + T (8*256^2) + M (8*256^2)
  const size_t perS = 2*(size_t)131072 + 2*(size_t)524288;
  size_t ws_f = ws_size / sizeof(float);
  int nb = 64;
  while (nb > 1 && small_end + (size_t)nb*perS > ws_f) nb >>= 1;

  size_t o_X = small_end;
  size_t o_D = o_X + (size_t)nb*131072;
  size_t o_T = o_D + (size_t)nb*131072;
  size_t o_M = o_T + (size_t)nb*524288;
  unsigned* mn = (unsigned*)(ws + o_mn);

  gather_ctx_kernel<<<8, BLK, 0, stream>>>(ids, cache, ws + o_ctx);

  W1Args a1;
  a1.M[0]=Ur;  a1.out[0]=ws+o_ur;
  a1.M[1]=Vr;  a1.out[1]=ws+o_vr;
  a1.M[2]=Ut;  a1.out[2]=ws+o_ut;
  a1.M[3]=Vt;  a1.out[3]=ws+o_vt;
  a1.M[4]=Um;  a1.out[4]=ws+o_um;
  a1.M[5]=Vm;  a1.out[5]=ws+o_vm;
  a1.M[6]=Br;  a1.out[6]=ws+o_br;
  a1.M[7]=Bt;  a1.out[7]=ws+o_bt;
  a1.M[8]=Bm;  a1.out[8]=ws+o_bm;
  a1.M[9]=Uo;  a1.out[9]=ws+o_uo;
  a1.M[10]=Vo; a1.out[10]=ws+o_vo;
  a1.M[11]=Bo; a1.out[11]=ws+o_bo;
  w1_kernel<<<256, BLK, 0, stream>>>(ws + o_ctx, a1);

  W2Args a2;
  a2.W[0]=Wr; a2.u[0]=ws+o_ur; a2.v[0]=ws+o_vr; a2.out[0]=ws+o_wr;
  a2.W[1]=Wt; a2.u[1]=ws+o_ut; a2.v[1]=ws+o_vt; a2.out[1]=ws+o_wt;
  a2.W[2]=Wm; a2.u[2]=ws+o_um; a2.v[2]=ws+o_vm; a2.out[2]=ws+o_wm;
  a2.W[3]=Wo; a2.u[3]=ws+o_uo; a2.v[3]=ws+o_vo; a2.out[3]=ws+o_wo;
  w2_kernel<<<256, BLK, 0, stream>>>(a2);

  for (int b0 = 0; b0 < 64; b0 += nb){
    gather_x_kernel<<<grid_for((long long)nb*2048), BLK, 0, stream>>>(
        ids, lat, ws+o_X, b0, nb);
    int maps = nb*8;
    init_min_kernel<<<(4*3*maps + BLK-1)/BLK, BLK, 0, stream>>>(mn, 4*3*maps);
    int H = 16;
    for (int s = 0; s < 4; ++s){
      int Ho = 2*H;
      int tprR = (H >= 32) ? H/32 : 1;
      int tprO = Ho/32;
      int gR = nb*tprR*tprR;
      int gT = nb*tprO*tprO;
      int gM = nb*tprO*tprO;
      unsigned* mns = mn + (size_t)s*3*maps;
      conv3_fused<<<gR+gT+gM, BLK, 0, stream>>>(
          ws+o_X, ws+o_wr, ws+o_br, ws+o_wt, ws+o_bt, ws+o_wm, ws+o_bm,
          ws+o_D, ws+o_T, ws+o_M, mns, maps, H, b0, s, tprR, tprO, gR, gT);
      if (s < 3){
        long long totalq = (long long)maps*H*H;
        combine_kernel<<<grid_for(totalq), BLK, 0, stream>>>(
            ws+o_D, ws+o_T, ws+o_M, mns, maps, ws+o_X, H, (int)totalq);
      } else {
        long long totalf = (long long)nb*16384;
        combineF_kernel<<<grid_for(totalf), BLK, 0, stream>>>(
            ws+o_D, ws+o_T, ws+o_M, mns, maps, ws+o_wo, ws+o_bo, out, b0, (int)totalf);
      }
      H = Ho;
    }
  }
}

// Round 14
// 1206.294 us; speedup vs baseline: 1.0562x; 1.0562x over previous
//
#include <hip/hip_runtime.h>
#include <math.h>

// ExperimentalModel_1752346656819: 4-stage dynamic-conv decoder, fp32 end-to-end.
// R13: packed-FP32 conv math — adjacent output channels paired into <2 x float>
// accumulators so the inner loops emit v_pk_fma_f32 (2 MACs/instr, full rate on
// CDNA). Weights already [q][o]-contiguous -> 8B-aligned float2 loads. Per-
// accumulator FP order preserved (bitwise-identical output). Structure = R12.

#define BLK 256
#define EF 2.7182818284590452f

typedef float v2f __attribute__((ext_vector_type(2)));

struct W1Args { const float* M[12]; float* out[12]; };
struct W2Args { const float* W[4]; const float* u[4]; const float* v[4]; float* out[4]; };

__device__ __forceinline__ float dln_one(float y, float m){
  float a = fabsf(y) - m;
  float v = __logf(__logf(a + EF) + 0.01f);
  return (y > 0.0f) ? v : -v;
}

__global__ void gather_ctx_kernel(const int* __restrict__ ids,
                                  const float* __restrict__ cache,
                                  float* __restrict__ ctx){
  int e = blockIdx.x*blockDim.x + threadIdx.x;
  if (e < 64*32){
    int b = e >> 5, l = e & 31;
    ctx[e] = cache[(size_t)ids[b]*32 + l];
  }
}

__global__ void gather_x_kernel(const int* __restrict__ ids,
                                const float* __restrict__ lat,
                                float* __restrict__ X, int b0, int nb){
  int total = nb*2048;
  int e = blockIdx.x*blockDim.x + threadIdx.x;
  if (e < total){
    int bl = e >> 11;
    int r  = e & 2047;
    X[e] = lat[(size_t)ids[b0+bl]*2048 + r];
  }
}

__global__ void w1_kernel(const float* __restrict__ ctx, W1Args args){
  const int S[12] = {4,4,4,4,4,4,4,4,4,1,1,1};
  const int K[12] = {128,1152,128,2048,128,3200,8,8,8,48,128,3};
  int tid = blockIdx.x*blockDim.x + threadIdx.x;
  int nth = gridDim.x*blockDim.x;
  for (int seg = 0; seg < 12; ++seg){
    const float* M = args.M[seg];
    float* out = args.out[seg];
    int Ks = K[seg];
    int total = S[seg]*64*Ks;
    for (int e = tid; e < total; e += nth){
      int k = e % Ks;
      int b = (e / Ks) % 64;
      int s = e / (Ks*64);
      const float* Ms = M + (size_t)s*32*Ks + k;
      const float* cb = ctx + b*32;
      float acc = 0.f;
      #pragma unroll
      for (int l = 0; l < 32; ++l) acc += cb[l]*Ms[(size_t)l*Ks];
      out[e] = acc;
    }
  }
}

// Dynamic weights. Segs 0-2 TRANSPOSED to [s][b][i][p][q][o]; seg 3 [b][o][i].
__global__ void w2_kernel(W2Args args){
  const int S[4] = {4,4,4,1};
  const int O[4] = {8,8,8,3};
  const int K[4] = {72,128,200,8};
  const int KH[4] = {3,4,5,1};
  int tid = blockIdx.x*blockDim.x + threadIdx.x;
  int nth = gridDim.x*blockDim.x;
  for (int seg = 0; seg < 4; ++seg){
    int Os = O[seg], Ks = K[seg];
    int kh = KH[seg], kk = kh*kh;
    int total = S[seg]*64*Os*Ks;
    const float* Wt = args.W[seg];
    const float* u = args.u[seg];
    const float* v = args.v[seg];
    float* out = args.out[seg];
    for (int e = tid; e < total; e += nth){
      int k = e % Ks;
      int o = (e/Ks) % Os;
      int b = (e/(Ks*Os)) % 64;
      int s = e/(Ks*Os*64);
      const float* us = u + (size_t)(s*64+b)*16*Os;
      const float* vs = v + (size_t)(s*64+b)*16*Ks;
      float mod = 0.f;
      #pragma unroll
      for (int r = 0; r < 16; ++r) mod += us[r*Os+o]*vs[r*Ks+k];
      float val = Wt[(size_t)(s*Os+o)*Ks + k] * (1.0f + mod + 1e-3f);
      size_t dst;
      if (seg < 3){
        int i = k / kk, r2 = k - i*kk, p = r2 / kh, q = r2 - p*kh;
        dst = (size_t)(s*64+b)*(8*Ks) + (size_t)(((i*kh+p)*kh+q)*8 + o);
      } else {
        dst = (size_t)b*24 + o*8 + k;
      }
      out[dst] = val;
    }
  }
}

__global__ void init_min_kernel(unsigned* __restrict__ mn, int n){
  int e = blockIdx.x*blockDim.x + threadIdx.x;
  if (e < n) mn[e] = 0x7F800000u;   // +inf
}

// Fused per-stage conv kernel: blocks [0,gR) = 3x3 conv; [gR,gR+gT) = 4x4
// stride-2 transposed conv; [gR+gT, ...) = 5x5 conv on bilinear-up(log).
// LDS union: 3880 floats (convm: 2880 tile + 1000 lbuf) = 15.5 KB.
__global__ void __launch_bounds__(BLK) conv3_fused(
    const float* __restrict__ X,
    const float* __restrict__ wr, const float* __restrict__ br,
    const float* __restrict__ wt, const float* __restrict__ bt,
    const float* __restrict__ wm, const float* __restrict__ bm,
    float* __restrict__ D, float* __restrict__ T, float* __restrict__ M,
    unsigned* __restrict__ mn, int maps, int H, int b0, int s,
    int tprR, int tprO, int gR, int gT){
  __shared__ __align__(16) float smem[3880];
  const int bid = blockIdx.x;

  if (bid < gR){
    // ------------- 3x3 conv (pad 1), FOUR phases of 2 input ch -------------
    float* tile = smem;                       // 2*34*36 = 2448
    const int tiles = tprR*tprR;
    const int bl = bid / tiles;
    const int t  = bid - bl*tiles;
    const int Y0 = (t/tprR)*32, X0 = (t - (t/tprR)*tprR)*32;
    const int bg = b0 + bl;
    const float* wb = wr + (size_t)(s*64+bg)*576;
    const float* bb = br + (s*64+bg)*8;
    const int HW = H*H;
    const float* xb = X + (size_t)bl*8*HW;
    const int tx = threadIdx.x & 7, ty = threadIdx.x >> 3;
    const bool act = (Y0+ty < H) && (X0+4*tx < H);  // only false when H==16
    v2f a2[4][4];
    #pragma unroll
    for (int o2 = 0; o2 < 4; ++o2){
      v2f b2; b2.x = bb[2*o2]; b2.y = bb[2*o2+1];
      a2[o2][0]=b2; a2[o2][1]=b2; a2[o2][2]=b2; a2[o2][3]=b2;
    }
    #pragma unroll 1
    for (int ph = 0; ph < 4; ++ph){
      __syncthreads();
      {
        float vb[10];
        #pragma unroll
        for (int k = 0; k < 10; ++k){
          int e = threadIdx.x + k*BLK;
          float v = 0.f;
          if (e < 2448){
            int cc = e % 36; int rr = (e/36) % 34; int c2 = e/(36*34);
            int gy = Y0 - 1 + rr, gx = X0 - 1 + cc;
            if (cc < 34 && (unsigned)gy < (unsigned)H && (unsigned)gx < (unsigned)H)
              v = xb[(size_t)(ph*2 + c2)*HW + gy*H + gx];
          }
          vb[k] = v;
        }
        #pragma unroll
        for (int k = 0; k < 10; ++k){
          int e = threadIdx.x + k*BLK;
          if (e < 2448) tile[e] = vb[k];
        }
      }
      __syncthreads();
      #pragma unroll 1
      for (int i = 0; i < 2; ++i){
        const float* tch = tile + i*1224;
        const int ig = ph*2 + i;
        #pragma unroll
        for (int p = 0; p < 3; ++p){
          const float* row = tch + (ty+p)*36 + 4*tx;
          float4 c0 = *(const float4*)row;
          float4 c1 = *(const float4*)(row+4);
          float c[8] = {c0.x,c0.y,c0.z,c0.w,c1.x,c1.y,c1.z,c1.w};
          const v2f* wip2 = (const v2f*)(wb + (ig*3+p)*24);
          #pragma unroll
          for (int q = 0; q < 3; ++q){
            #pragma unroll
            for (int o2 = 0; o2 < 4; ++o2){
              v2f w2 = wip2[q*4+o2];
              a2[o2][0] += w2*c[q];   a2[o2][1] += w2*c[q+1];
              a2[o2][2] += w2*c[q+2]; a2[o2][3] += w2*c[q+3];
            }
          }
        }
      }
    }
    float lm[8];
    #pragma unroll
    for (int o = 0; o < 8; ++o){
      const int o2 = o >> 1;
      float b0v = (o&1) ? a2[o2][0].y : a2[o2][0].x;
      float b1v = (o&1) ? a2[o2][1].y : a2[o2][1].x;
      float b2v = (o&1) ? a2[o2][2].y : a2[o2][2].x;
      float b3v = (o&1) ? a2[o2][3].y : a2[o2][3].x;
      float v = act ? fminf(fminf(fabsf(b0v),fabsf(b1v)),
                            fminf(fabsf(b2v),fabsf(b3v))) : 3.4e38f;
      #pragma unroll
      for (int off = 32; off > 0; off >>= 1) v = fminf(v, __shfl_xor(v, off));
      lm[o] = v;
      if (act){
        *(float4*)(D + ((size_t)(bl*8+o))*HW + (Y0+ty)*H + X0 + 4*tx) =
            make_float4(b0v,b1v,b2v,b3v);
      }
    }
    if ((threadIdx.x & 63) == 0){
      #pragma unroll
      for (int o = 0; o < 8; ++o) atomicMin(mn + bl*8 + o, __float_as_uint(lm[o]));
    }
    return;
  }

  if (bid < gR + gT){
    // ------- 4x4 stride-2 transposed conv of (-x) (pad 1), 32x32 out tile -------
    float* tile = smem;                       // 8*18*20 = 2880
    const int idx = bid - gR;
    const int tiles = tprO*tprO;
    const int bl = idx / tiles;
    const int t  = idx - bl*tiles;
    const int Y0 = (t/tprO)*32, X0 = (t - (t/tprO)*tprO)*32;  // output coords
    const int bg = b0 + bl;
    const float* wb = wt + (size_t)(s*64+bg)*1024;
    const float* bb = bt + (s*64+bg)*8;
    const int Ho = 2*H, HWo = Ho*Ho, HW = H*H;
    const float* xb = X + (size_t)bl*8*HW;
    const int ry0 = Y0/2 - 1, rx0 = X0/2 - 1;
    {
      float vb[12];
      #pragma unroll
      for (int k = 0; k < 12; ++k){
        int e = threadIdx.x + k*BLK;
        float v = 0.f;
        if (e < 2880){
          int cc = e % 20; int rr = (e/20) % 18; int ch = e/(20*18);
          int gy = ry0 + rr, gx = rx0 + cc;
          if (cc < 18 && (unsigned)gy < (unsigned)H && (unsigned)gx < (unsigned)H)
            v = xb[(size_t)ch*HW + gy*H + gx];
        }
        vb[k] = v;
      }
      #pragma unroll
      for (int k = 0; k < 12; ++k){
        int e = threadIdx.x + k*BLK;
        if (e < 2880) tile[e] = vb[k];
      }
    }
    __syncthreads();
    const int tx = threadIdx.x & 7;
    const int ty2 = threadIdx.x >> 3;
    const int row = (ty2 < 16) ? 2*ty2 : 2*(ty2-16)+1;   // wave-parity-uniform
    const int yodd = __builtin_amdgcn_readfirstlane(row & 1);
    const int half = row >> 1;
    const int pA = yodd ? 0 : 1, rA = yodd ? half+2 : half+1;
    const int pB = yodd ? 2 : 3, rB = yodd ? half+1 : half;
    v2f a2[4][4];
    #pragma unroll
    for (int o2 = 0; o2 < 4; ++o2){
      v2f b2; b2.x = bb[2*o2]; b2.y = bb[2*o2+1];
      a2[o2][0]=b2; a2[o2][1]=b2; a2[o2][2]=b2; a2[o2][3]=b2;
    }
    #pragma unroll 1
    for (int i = 0; i < 8; ++i){
      #pragma unroll
      for (int rt = 0; rt < 2; ++rt){
        const int p = rt ? pB : pA;
        const int ri = rt ? rB : rA;
        const float* rowp = tile + i*360 + ri*20 + 2*tx;
        float e0 = rowp[0], e1 = rowp[1], e2 = rowp[2], e3 = rowp[3];
        const v2f* wip2 = (const v2f*)(wb + (i*4+p)*32);   // [q][o], uniform
        #pragma unroll
        for (int o2 = 0; o2 < 4; ++o2){
          v2f W0 = wip2[o2],    W1 = wip2[4+o2];
          v2f W2 = wip2[8+o2],  W3 = wip2[12+o2];
          a2[o2][0] -= W1*e1; a2[o2][2] -= W1*e2;  // x even, q=1
          a2[o2][0] -= W3*e0; a2[o2][2] -= W3*e1;  // x even, q=3
          a2[o2][1] -= W0*e2; a2[o2][3] -= W0*e3;  // x odd,  q=0
          a2[o2][1] -= W2*e1; a2[o2][3] -= W2*e2;  // x odd,  q=2
        }
      }
    }
    float lm[8];
    #pragma unroll
    for (int o = 0; o < 8; ++o){
      const int o2 = o >> 1;
      float b0v = (o&1) ? a2[o2][0].y : a2[o2][0].x;
      float b1v = (o&1) ? a2[o2][1].y : a2[o2][1].x;
      float b2v = (o&1) ? a2[o2][2].y : a2[o2][2].x;
      float b3v = (o&1) ? a2[o2][3].y : a2[o2][3].x;
      float v = fminf(fminf(fabsf(b0v),fabsf(b1v)),
                      fminf(fabsf(b2v),fabsf(b3v)));
      #pragma unroll
      for (int off = 32; off > 0; off >>= 1) v = fminf(v, __shfl_xor(v, off));
      lm[o] = v;
      *(float4*)(T + ((size_t)(bl*8+o))*HWo + (Y0+row)*Ho + X0 + 4*tx) =
          make_float4(b0v,b1v,b2v,b3v);
    }
    if ((threadIdx.x & 63) == 0){
      #pragma unroll
      for (int o = 0; o < 8; ++o)
        atomicMin(mn + maps + bl*8 + o, __float_as_uint(lm[o]));
    }
    return;
  }

  // --- 5x5 conv (pad 2) on bilinear-up(log(|X|+1)); FOUR phases of 2 ch ---
  {
    float* tile = smem;                       // 2*36*40 = 2880
    float* lbuf = smem + 2880;                // 2*20*25 = 1000
    const int idx = bid - gR - gT;
    const int tiles = tprO*tprO;
    const int bl = idx / tiles;
    const int t  = idx - bl*tiles;
    const int Y0 = (t/tprO)*32, X0 = (t - (t/tprO)*tprO)*32;
    const int bg = b0 + bl;
    const float* wb = wm + (size_t)(s*64+bg)*1600;
    const float* bb = bm + (s*64+bg)*8;
    const int Hi = 2*H;
    const int Hq = H, HWq = Hq*Hq;
    const int HW = Hi*Hi;
    const float* xb = X + (size_t)bl*8*HWq;
    const int LY0 = ((Y0-2)>>1) - 1;
    const int LX0 = ((X0-2)>>1) - 1;
    const int tx = threadIdx.x & 7, ty = threadIdx.x >> 3;
    v2f a2[4][4];
    #pragma unroll
    for (int o2 = 0; o2 < 4; ++o2){
      v2f b2; b2.x = bb[2*o2]; b2.y = bb[2*o2+1];
      a2[o2][0]=b2; a2[o2][1]=b2; a2[o2][2]=b2; a2[o2][3]=b2;
    }
    #pragma unroll 1
    for (int ph = 0; ph < 4; ++ph){
      __syncthreads();
      // stage quarter-res log halo: 2 ch x 20 x 25(stride, 22 used) = 1000
      #pragma unroll
      for (int k = 0; k < 4; ++k){
        int e = threadIdx.x + k*BLK;
        if (e < 1000){
          int c2 = e/500; int r2 = e - c2*500; int rr = r2/25; int cc = r2 - rr*25;
          int ly = LY0 + rr, lx = LX0 + cc;
          float v = 0.f;
          if (cc < 22 && (unsigned)ly < (unsigned)Hq && (unsigned)lx < (unsigned)Hq){
            float xv = xb[(size_t)(ph*2 + c2)*HWq + ly*Hq + lx];
            v = __logf(fabsf(xv) + 1.0f);
          }
          lbuf[e] = v;
        }
      }
      __syncthreads();
      // expand 2x bilinear (half-pixel, edge clamp) into 36x40 halo tile
      #pragma unroll 1
      for (int e = threadIdx.x; e < 2880; e += BLK){
        int c2 = e/1440; int r2 = e - c2*1440; int rr = r2/40; int cc = r2 - rr*40;
        int gy = Y0 - 2 + rr, gx = X0 - 2 + cc;
        float f = 0.f;
        if (cc < 36 && (unsigned)gy < (unsigned)Hi && (unsigned)gx < (unsigned)Hi){
          int jy = gy >> 1;
          int ny = (gy & 1) ? ((jy+1 < Hq) ? jy+1 : Hq-1) : ((jy > 0) ? jy-1 : 0);
          int jx = gx >> 1;
          int nx = (gx & 1) ? ((jx+1 < Hq) ? jx+1 : Hq-1) : ((jx > 0) ? jx-1 : 0);
          const float* lb = lbuf + c2*500;
          float f00 = lb[(jy-LY0)*25 + (jx-LX0)];
          float f01 = lb[(jy-LY0)*25 + (nx-LX0)];
          float f10 = lb[(ny-LY0)*25 + (jx-LX0)];
          float f11 = lb[(ny-LY0)*25 + (nx-LX0)];
          f = 0.5625f*f00 + 0.1875f*(f01 + f10) + 0.0625f*f11;
        }
        tile[e] = f;
      }
      __syncthreads();
      #pragma unroll 1
      for (int i = 0; i < 2; ++i){
        const float* tch = tile + i*1440;
        const int ig = ph*2 + i;
        #pragma unroll
        for (int p = 0; p < 5; ++p){
          const float* row = tch + (ty+p)*40 + 4*tx;
          float4 c0 = *(const float4*)row;
          float4 c1 = *(const float4*)(row+4);
          float c[8] = {c0.x,c0.y,c0.z,c0.w,c1.x,c1.y,c1.z,c1.w};
          const v2f* wip2 = (const v2f*)(wb + (ig*5+p)*40);   // [q][o], uniform
          #pragma unroll
          for (int q = 0; q < 5; ++q){
            #pragma unroll
            for (int o2 = 0; o2 < 4; ++o2){
              v2f w2 = wip2[q*4+o2];
              a2[o2][0] += w2*c[q];   a2[o2][1] += w2*c[q+1];
              a2[o2][2] += w2*c[q+2]; a2[o2][3] += w2*c[q+3];
            }
          }
        }
      }
    }
    float lm[8];
    #pragma unroll
    for (int o = 0; o < 8; ++o){
      const int o2 = o >> 1;
      float b0v = (o&1) ? a2[o2][0].y : a2[o2][0].x;
      float b1v = (o&1) ? a2[o2][1].y : a2[o2][1].x;
      float b2v = (o&1) ? a2[o2][2].y : a2[o2][2].x;
      float b3v = (o&1) ? a2[o2][3].y : a2[o2][3].x;
      float v = fminf(fminf(fabsf(b0v),fabsf(b1v)),
                      fminf(fabsf(b2v),fabsf(b3v)));
      #pragma unroll
      for (int off = 32; off > 0; off >>= 1) v = fminf(v, __shfl_xor(v, off));
      lm[o] = v;
      *(float4*)(M + ((size_t)(bl*8+o))*HW + (Y0+ty)*Hi + X0 + 4*tx) =
          make_float4(b0v,b1v,b2v,b3v);
    }
    if ((threadIdx.x & 63) == 0){
      #pragma unroll
      for (int o = 0; o < 8; ++o)
        atomicMin(mn + 2*maps + bl*8 + o, __float_as_uint(lm[o]));
    }
  }
}

// s<3: next_x = (dln(Dr)[nearest-up] + dln(Dt)) * dln(Dm), into X. Quarter-px threads.
__global__ void combine_kernel(const float* __restrict__ dr, const float* __restrict__ dt,
                               const float* __restrict__ dm,
                               const unsigned* __restrict__ mn, int maps,
                               float* __restrict__ outx, int H, int total){
  int Ho = 2*H, HWo = Ho*Ho, HW = H*H;
  for (int e = blockIdx.x*blockDim.x + threadIdx.x; e < total; e += gridDim.x*blockDim.x){
    int m = e / HW;
    int qpx = e - m*HW;
    int qy = qpx / H, qx = qpx - qy*H;
    float mr = __uint_as_float(mn[m]);
    float mt = __uint_as_float(mn[maps + m]);
    float mm = __uint_as_float(mn[2*maps + m]);
    float r = dln_one(dr[(size_t)m*HW + qpx], mr);
    #pragma unroll
    for (int dy = 0; dy < 2; ++dy){
      size_t base = (size_t)m*HWo + (2*qy+dy)*Ho + 2*qx;
      float2 tv = *(const float2*)(dt + base);
      float2 mv = *(const float2*)(dm + base);
      float2 ov;
      ov.x = (r + dln_one(tv.x, mt)) * dln_one(mv.x, mm);
      ov.y = (r + dln_one(tv.y, mt)) * dln_one(mv.y, mm);
      *(float2*)(outx + base) = ov;
    }
  }
}

// s==3: combine + final dynamic 1x1 conv (8->3 ch) fused, writes d_out.
__global__ void combineF_kernel(const float* __restrict__ dr, const float* __restrict__ dt,
                                const float* __restrict__ dm,
                                const unsigned* __restrict__ mn, int maps,
                                const float* __restrict__ wo, const float* __restrict__ bo,
                                float* __restrict__ out, int b0, int total){
  for (int e = blockIdx.x*blockDim.x + threadIdx.x; e < total; e += gridDim.x*blockDim.x){
    int bl = e >> 14;
    int qpx = e & 16383;
    int qy = qpx >> 7, qx = qpx & 127;
    int bg = b0 + bl;
    float r[8], mtv[8], mmv[8];
    #pragma unroll
    for (int o = 0; o < 8; ++o){
      int m = bl*8 + o;
      float mr = __uint_as_float(mn[m]);
      mtv[o] = __uint_as_float(mn[maps + m]);
      mmv[o] = __uint_as_float(mn[2*maps + m]);
      r[o] = dln_one(dr[(size_t)m*16384 + qpx], mr);
    }
    #pragma unroll
    for (int dy = 0; dy < 2; ++dy){
      int y = 2*qy + dy, xx = 2*qx;
      float2 acc[3];
      #pragma unroll
      for (int of = 0; of < 3; ++of){
        float b = bo[bg*3 + of];
        acc[of].x = b; acc[of].y = b;
      }
      #pragma unroll
      for (int o = 0; o < 8; ++o){
        size_t base = (size_t)(bl*8+o)*65536 + y*256 + xx;
        float2 tv = *(const float2*)(dt + base);
        float2 mv = *(const float2*)(dm + base);
        float vx = (r[o] + dln_one(tv.x, mtv[o])) * dln_one(mv.x, mmv[o]);
        float vy = (r[o] + dln_one(tv.y, mtv[o])) * dln_one(mv.y, mmv[o]);
        #pragma unroll
        for (int of = 0; of < 3; ++of){
          float w = wo[bg*24 + of*8 + o];
          acc[of].x += w*vx; acc[of].y += w*vy;
        }
      }
      #pragma unroll
      for (int of = 0; of < 3; ++of){
        *(float2*)(out + ((size_t)(bg*3 + of))*65536 + y*256 + xx) = acc[of];
      }
    }
  }
}

static inline int grid_for(long long total){
  long long g = (total + BLK - 1) / BLK;
  if (g > 16384) g = 16384;
  if (g < 1) g = 1;
  return (int)g;
}

extern "C" void kernel_launch(void* const* d_in, const int* in_sizes, int n_in,
                              void* d_out, int out_size, void* d_ws, size_t ws_size,
                              hipStream_t stream){
  (void)in_sizes; (void)n_in; (void)out_size;
  const int*   ids   = (const int*)d_in[0];
  const float* cache = (const float*)d_in[1];
  const float* lat   = (const float*)d_in[2];
  const float* Wr = (const float*)d_in[3];
  const float* Ur = (const float*)d_in[4];
  const float* Vr = (const float*)d_in[5];
  const float* Br = (const float*)d_in[6];
  const float* Wt = (const float*)d_in[7];
  const float* Ut = (const float*)d_in[8];
  const float* Vt = (const float*)d_in[9];
  const float* Bt = (const float*)d_in[10];
  const float* Wm = (const float*)d_in[11];
  const float* Um = (const float*)d_in[12];
  const float* Vm = (const float*)d_in[13];
  const float* Bm = (const float*)d_in[14];
  const float* Wo = (const float*)d_in[15];
  const float* Uo = (const float*)d_in[16];
  const float* Vo = (const float*)d_in[17];
  const float* Bo = (const float*)d_in[18];
  float* out = (float*)d_out;
  float* ws  = (float*)d_ws;

  size_t off = 0;
  auto alloc = [&](size_t n){ size_t o = off; off += n; return o; };
  size_t o_ctx = alloc(2048);
  size_t o_ur = alloc(4*64*128),  o_vr = alloc(4*64*1152);
  size_t o_ut = alloc(4*64*128),  o_vt = alloc(4*64*2048);
  size_t o_um = alloc(4*64*128),  o_vm = alloc(4*64*3200);
  size_t o_br = alloc(4*64*8), o_bt = alloc(4*64*8), o_bm = alloc(4*64*8);
  size_t o_uo = alloc(64*48), o_vo = alloc(64*128), o_bo = alloc(64*3);
  size_t o_wr = alloc(4*64*8*72), o_wt = alloc(4*64*8*128), o_wm = alloc(4*64*8*200);
  size_t o_wo = alloc(64*24);
  size_t o_mn = alloc(4*3*512);          // [stage][3][maps]
  size_t small_end = off;

  // per sample: X (8*128^2) + D (8*128^2) + T (8*256^2) + M (8*256^2)
  const size_t perS = 2*(size_t)131072 + 2*(size_t)524288;
  size_t ws_f = ws_size / sizeof(float);
  int nb = 64;
  while (nb > 1 && small_end + (size_t)nb*perS > ws_f) nb >>= 1;

  size_t o_X = small_end;
  size_t o_D = o_X + (size_t)nb*131072;
  size_t o_T = o_D + (size_t)nb*131072;
  size_t o_M = o_T + (size_t)nb*524288;
  unsigned* mn = (unsigned*)(ws + o_mn);

  gather_ctx_kernel<<<8, BLK, 0, stream>>>(ids, cache, ws + o_ctx);

  W1Args a1;
  a1.M[0]=Ur;  a1.out[0]=ws+o_ur;
  a1.M[1]=Vr;  a1.out[1]=ws+o_vr;
  a1.M[2]=Ut;  a1.out[2]=ws+o_ut;
  a1.M[3]=Vt;  a1.out[3]=ws+o_vt;
  a1.M[4]=Um;  a1.out[4]=ws+o_um;
  a1.M[5]=Vm;  a1.out[5]=ws+o_vm;
  a1.M[6]=Br;  a1.out[6]=ws+o_br;
  a1.M[7]=Bt;  a1.out[7]=ws+o_bt;
  a1.M[8]=Bm;  a1.out[8]=ws+o_bm;
  a1.M[9]=Uo;  a1.out[9]=ws+o_uo;
  a1.M[10]=Vo; a1.out[10]=ws+o_vo;
  a1.M[11]=Bo; a1.out[11]=ws+o_bo;
  w1_kernel<<<256, BLK, 0, stream>>>(ws + o_ctx, a1);

  W2Args a2;
  a2.W[0]=Wr; a2.u[0]=ws+o_ur; a2.v[0]=ws+o_vr; a2.out[0]=ws+o_wr;
  a2.W[1]=Wt; a2.u[1]=ws+o_ut; a2.v[1]=ws+o_vt; a2.out[1]=ws+o_wt;
  a2.W[2]=Wm; a2.u[2]=ws+o_um; a2.v[2]=ws+o_vm; a2.out[2]=ws+o_wm;
  a2.W[3]=Wo; a2.u[3]=ws+o_uo; a2.v[3]=ws+o_vo; a2.out[3]=ws+o_wo;
  w2_kernel<<<256, BLK, 0, stream>>>(a2);

  for (int b0 = 0; b0 < 64; b0 += nb){
    gather_x_kernel<<<grid_for((long long)nb*2048), BLK, 0, stream>>>(
        ids, lat, ws+o_X, b0, nb);
    int maps = nb*8;
    init_min_kernel<<<(4*3*maps + BLK-1)/BLK, BLK, 0, stream>>>(mn, 4*3*maps);
    int H = 16;
    for (int s = 0; s < 4; ++s){
      int Ho = 2*H;
      int tprR = (H >= 32) ? H/32 : 1;
      int tprO = Ho/32;
      int gR = nb*tprR*tprR;
      int gT = nb*tprO*tprO;
      int gM = nb*tprO*tprO;
      unsigned* mns = mn + (size_t)s*3*maps;
      conv3_fused<<<gR+gT+gM, BLK, 0, stream>>>(
          ws+o_X, ws+o_wr, ws+o_br, ws+o_wt, ws+o_bt, ws+o_wm, ws+o_bm,
          ws+o_D, ws+o_T, ws+o_M, mns, maps, H, b0, s, tprR, tprO, gR, gT);
      if (s < 3){
        long long totalq = (long long)maps*H*H;
        combine_kernel<<<grid_for(totalq), BLK, 0, stream>>>(
            ws+o_D, ws+o_T, ws+o_M, mns, maps, ws+o_X, H, (int)totalq);
      } else {
        long long totalf = (long long)nb*16384;
        combineF_kernel<<<grid_for(totalf), BLK, 0, stream>>>(
            ws+o_D, ws+o_T, ws+o_M, mns, maps, ws+o_wo, ws+o_bo, out, b0, (int)totalf);
      }
      H = Ho;
    }
  }
}

// Round 15
// 1110.610 us; speedup vs baseline: 1.1472x; 1.0862x over previous
//
#include <hip/hip_runtime.h>
#include <math.h>

// ExperimentalModel_1752346656819: 4-stage dynamic-conv decoder, fp32 end-to-end.
// R14: (1) register-prefetch software pipeline in convm/convr phase loops —
// next phase's global loads issue before the current phase's compute, hiding
// HBM/L2 latency behind expand+consume; logf applied at store (prefetch regs
// hold raw values; invalid=0 -> log(1)=0, bitwise-identical output).
// (2) longest-first grid order: convm | convt | convr (was reverse) so the
// long blocks start first and the dispatch tail is cheap convr blocks.

#define BLK 256
#define EF 2.7182818284590452f

typedef float v2f __attribute__((ext_vector_type(2)));

struct W1Args { const float* M[12]; float* out[12]; };
struct W2Args { const float* W[4]; const float* u[4]; const float* v[4]; float* out[4]; };

__device__ __forceinline__ float dln_one(float y, float m){
  float a = fabsf(y) - m;
  float v = __logf(__logf(a + EF) + 0.01f);
  return (y > 0.0f) ? v : -v;
}

__global__ void gather_ctx_kernel(const int* __restrict__ ids,
                                  const float* __restrict__ cache,
                                  float* __restrict__ ctx){
  int e = blockIdx.x*blockDim.x + threadIdx.x;
  if (e < 64*32){
    int b = e >> 5, l = e & 31;
    ctx[e] = cache[(size_t)ids[b]*32 + l];
  }
}

__global__ void gather_x_kernel(const int* __restrict__ ids,
                                const float* __restrict__ lat,
                                float* __restrict__ X, int b0, int nb){
  int total = nb*2048;
  int e = blockIdx.x*blockDim.x + threadIdx.x;
  if (e < total){
    int bl = e >> 11;
    int r  = e & 2047;
    X[e] = lat[(size_t)ids[b0+bl]*2048 + r];
  }
}

__global__ void w1_kernel(const float* __restrict__ ctx, W1Args args){
  const int S[12] = {4,4,4,4,4,4,4,4,4,1,1,1};
  const int K[12] = {128,1152,128,2048,128,3200,8,8,8,48,128,3};
  int tid = blockIdx.x*blockDim.x + threadIdx.x;
  int nth = gridDim.x*blockDim.x;
  for (int seg = 0; seg < 12; ++seg){
    const float* M = args.M[seg];
    float* out = args.out[seg];
    int Ks = K[seg];
    int total = S[seg]*64*Ks;
    for (int e = tid; e < total; e += nth){
      int k = e % Ks;
      int b = (e / Ks) % 64;
      int s = e / (Ks*64);
      const float* Ms = M + (size_t)s*32*Ks + k;
      const float* cb = ctx + b*32;
      float acc = 0.f;
      #pragma unroll
      for (int l = 0; l < 32; ++l) acc += cb[l]*Ms[(size_t)l*Ks];
      out[e] = acc;
    }
  }
}

// Dynamic weights. Segs 0-2 TRANSPOSED to [s][b][i][p][q][o]; seg 3 [b][o][i].
__global__ void w2_kernel(W2Args args){
  const int S[4] = {4,4,4,1};
  const int O[4] = {8,8,8,3};
  const int K[4] = {72,128,200,8};
  const int KH[4] = {3,4,5,1};
  int tid = blockIdx.x*blockDim.x + threadIdx.x;
  int nth = gridDim.x*blockDim.x;
  for (int seg = 0; seg < 4; ++seg){
    int Os = O[seg], Ks = K[seg];
    int kh = KH[seg], kk = kh*kh;
    int total = S[seg]*64*Os*Ks;
    const float* Wt = args.W[seg];
    const float* u = args.u[seg];
    const float* v = args.v[seg];
    float* out = args.out[seg];
    for (int e = tid; e < total; e += nth){
      int k = e % Ks;
      int o = (e/Ks) % Os;
      int b = (e/(Ks*Os)) % 64;
      int s = e/(Ks*Os*64);
      const float* us = u + (size_t)(s*64+b)*16*Os;
      const float* vs = v + (size_t)(s*64+b)*16*Ks;
      float mod = 0.f;
      #pragma unroll
      for (int r = 0; r < 16; ++r) mod += us[r*Os+o]*vs[r*Ks+k];
      float val = Wt[(size_t)(s*Os+o)*Ks + k] * (1.0f + mod + 1e-3f);
      size_t dst;
      if (seg < 3){
        int i = k / kk, r2 = k - i*kk, p = r2 / kh, q = r2 - p*kh;
        dst = (size_t)(s*64+b)*(8*Ks) + (size_t)(((i*kh+p)*kh+q)*8 + o);
      } else {
        dst = (size_t)b*24 + o*8 + k;
      }
      out[dst] = val;
    }
  }
}

__global__ void init_min_kernel(unsigned* __restrict__ mn, int n){
  int e = blockIdx.x*blockDim.x + threadIdx.x;
  if (e < n) mn[e] = 0x7F800000u;   // +inf
}

// Fused per-stage conv kernel, LONGEST-FIRST order:
// blocks [0,g1) = 5x5 conv on bilinear-up(log) (convm);
// [g1,g2) = 4x4 stride-2 transposed conv (convt); [g2,...) = 3x3 conv (convr).
// LDS union: 3880 floats = 15.5 KB.
__global__ void __launch_bounds__(BLK) conv3_fused(
    const float* __restrict__ X,
    const float* __restrict__ wr, const float* __restrict__ br,
    const float* __restrict__ wt, const float* __restrict__ bt,
    const float* __restrict__ wm, const float* __restrict__ bm,
    float* __restrict__ D, float* __restrict__ T, float* __restrict__ M,
    unsigned* __restrict__ mn, int maps, int H, int b0, int s,
    int tprR, int tprO, int g1, int g2){
  __shared__ __align__(16) float smem[3880];
  const int bid = blockIdx.x;

  if (bid < g1){
    // --- 5x5 conv (pad 2) on bilinear-up(log(|X|+1)); 4 phases of 2 ch,
    //     register-prefetch pipeline on the quarter-res halo loads ---
    float* tile = smem;                       // 2*36*40 = 2880
    float* lbuf = smem + 2880;                // 2*20*25 = 1000
    const int idx = bid;
    const int tiles = tprO*tprO;
    const int bl = idx / tiles;
    const int t  = idx - bl*tiles;
    const int Y0 = (t/tprO)*32, X0 = (t - (t/tprO)*tprO)*32;
    const int bg = b0 + bl;
    const float* wb = wm + (size_t)(s*64+bg)*1600;
    const float* bb = bm + (s*64+bg)*8;
    const int Hi = 2*H;
    const int Hq = H, HWq = Hq*Hq;
    const int HW = Hi*Hi;
    const float* xb = X + (size_t)bl*8*HWq;
    const int LY0 = ((Y0-2)>>1) - 1;
    const int LX0 = ((X0-2)>>1) - 1;
    const int tx = threadIdx.x & 7, ty = threadIdx.x >> 3;
    v2f a2[4][4];
    #pragma unroll
    for (int o2 = 0; o2 < 4; ++o2){
      v2f b2; b2.x = bb[2*o2]; b2.y = bb[2*o2+1];
      a2[o2][0]=b2; a2[o2][1]=b2; a2[o2][2]=b2; a2[o2][3]=b2;
    }
    float pre[4];
    #pragma unroll
    for (int k = 0; k < 4; ++k){
      int e = threadIdx.x + k*BLK;
      float v = 0.f;
      if (e < 1000){
        int c2 = e/500; int r2 = e - c2*500; int rr = r2/25; int cc = r2 - rr*25;
        int ly = LY0 + rr, lx = LX0 + cc;
        if (cc < 22 && (unsigned)ly < (unsigned)Hq && (unsigned)lx < (unsigned)Hq)
          v = xb[(size_t)c2*HWq + ly*Hq + lx];
      }
      pre[k] = v;
    }
    #pragma unroll 1
    for (int ph = 0; ph < 4; ++ph){
      if (ph > 0) __syncthreads();
      #pragma unroll
      for (int k = 0; k < 4; ++k){
        int e = threadIdx.x + k*BLK;
        if (e < 1000) lbuf[e] = __logf(fabsf(pre[k]) + 1.0f);
      }
      __syncthreads();
      if (ph < 3){
        #pragma unroll
        for (int k = 0; k < 4; ++k){
          int e = threadIdx.x + k*BLK;
          float v = 0.f;
          if (e < 1000){
            int c2 = e/500; int r2 = e - c2*500; int rr = r2/25; int cc = r2 - rr*25;
            int ly = LY0 + rr, lx = LX0 + cc;
            if (cc < 22 && (unsigned)ly < (unsigned)Hq && (unsigned)lx < (unsigned)Hq)
              v = xb[(size_t)((ph+1)*2 + c2)*HWq + ly*Hq + lx];
          }
          pre[k] = v;
        }
      }
      // expand 2x bilinear (half-pixel, edge clamp) into 36x40 halo tile
      #pragma unroll 1
      for (int e = threadIdx.x; e < 2880; e += BLK){
        int c2 = e/1440; int r2 = e - c2*1440; int rr = r2/40; int cc = r2 - rr*40;
        int gy = Y0 - 2 + rr, gx = X0 - 2 + cc;
        float f = 0.f;
        if (cc < 36 && (unsigned)gy < (unsigned)Hi && (unsigned)gx < (unsigned)Hi){
          int jy = gy >> 1;
          int ny = (gy & 1) ? ((jy+1 < Hq) ? jy+1 : Hq-1) : ((jy > 0) ? jy-1 : 0);
          int jx = gx >> 1;
          int nx = (gx & 1) ? ((jx+1 < Hq) ? jx+1 : Hq-1) : ((jx > 0) ? jx-1 : 0);
          const float* lb = lbuf + c2*500;
          float f00 = lb[(jy-LY0)*25 + (jx-LX0)];
          float f01 = lb[(jy-LY0)*25 + (nx-LX0)];
          float f10 = lb[(ny-LY0)*25 + (jx-LX0)];
          float f11 = lb[(ny-LY0)*25 + (nx-LX0)];
          f = 0.5625f*f00 + 0.1875f*(f01 + f10) + 0.0625f*f11;
        }
        tile[e] = f;
      }
      __syncthreads();
      #pragma unroll 1
      for (int i = 0; i < 2; ++i){
        const float* tch = tile + i*1440;
        const int ig = ph*2 + i;
        #pragma unroll
        for (int p = 0; p < 5; ++p){
          const float* row = tch + (ty+p)*40 + 4*tx;
          float4 c0 = *(const float4*)row;
          float4 c1 = *(const float4*)(row+4);
          float c[8] = {c0.x,c0.y,c0.z,c0.w,c1.x,c1.y,c1.z,c1.w};
          const v2f* wip2 = (const v2f*)(wb + (ig*5+p)*40);   // [q][o], uniform
          #pragma unroll
          for (int q = 0; q < 5; ++q){
            #pragma unroll
            for (int o2 = 0; o2 < 4; ++o2){
              v2f w2 = wip2[q*4+o2];
              a2[o2][0] += w2*c[q];   a2[o2][1] += w2*c[q+1];
              a2[o2][2] += w2*c[q+2]; a2[o2][3] += w2*c[q+3];
            }
          }
        }
      }
    }
    float lm[8];
    #pragma unroll
    for (int o = 0; o < 8; ++o){
      const int o2 = o >> 1;
      float b0v = (o&1) ? a2[o2][0].y : a2[o2][0].x;
      float b1v = (o&1) ? a2[o2][1].y : a2[o2][1].x;
      float b2v = (o&1) ? a2[o2][2].y : a2[o2][2].x;
      float b3v = (o&1) ? a2[o2][3].y : a2[o2][3].x;
      float v = fminf(fminf(fabsf(b0v),fabsf(b1v)),
                      fminf(fabsf(b2v),fabsf(b3v)));
      #pragma unroll
      for (int off = 32; off > 0; off >>= 1) v = fminf(v, __shfl_xor(v, off));
      lm[o] = v;
      *(float4*)(M + ((size_t)(bl*8+o))*HW + (Y0+ty)*Hi + X0 + 4*tx) =
          make_float4(b0v,b1v,b2v,b3v);
    }
    if ((threadIdx.x & 63) == 0){
      #pragma unroll
      for (int o = 0; o < 8; ++o)
        atomicMin(mn + 2*maps + bl*8 + o, __float_as_uint(lm[o]));
    }
    return;
  }

  if (bid < g2){
    // ------- 4x4 stride-2 transposed conv of (-x) (pad 1), 32x32 out tile -------
    float* tile = smem;                       // 8*18*20 = 2880
    const int idx = bid - g1;
    const int tiles = tprO*tprO;
    const int bl = idx / tiles;
    const int t  = idx - bl*tiles;
    const int Y0 = (t/tprO)*32, X0 = (t - (t/tprO)*tprO)*32;  // output coords
    const int bg = b0 + bl;
    const float* wb = wt + (size_t)(s*64+bg)*1024;
    const float* bb = bt + (s*64+bg)*8;
    const int Ho = 2*H, HWo = Ho*Ho, HW = H*H;
    const float* xb = X + (size_t)bl*8*HW;
    const int ry0 = Y0/2 - 1, rx0 = X0/2 - 1;
    {
      float vb[12];
      #pragma unroll
      for (int k = 0; k < 12; ++k){
        int e = threadIdx.x + k*BLK;
        float v = 0.f;
        if (e < 2880){
          int cc = e % 20; int rr = (e/20) % 18; int ch = e/(20*18);
          int gy = ry0 + rr, gx = rx0 + cc;
          if (cc < 18 && (unsigned)gy < (unsigned)H && (unsigned)gx < (unsigned)H)
            v = xb[(size_t)ch*HW + gy*H + gx];
        }
        vb[k] = v;
      }
      #pragma unroll
      for (int k = 0; k < 12; ++k){
        int e = threadIdx.x + k*BLK;
        if (e < 2880) tile[e] = vb[k];
      }
    }
    __syncthreads();
    const int tx = threadIdx.x & 7;
    const int ty2 = threadIdx.x >> 3;
    const int row = (ty2 < 16) ? 2*ty2 : 2*(ty2-16)+1;   // wave-parity-uniform
    const int yodd = __builtin_amdgcn_readfirstlane(row & 1);
    const int half = row >> 1;
    const int pA = yodd ? 0 : 1, rA = yodd ? half+2 : half+1;
    const int pB = yodd ? 2 : 3, rB = yodd ? half+1 : half;
    v2f a2[4][4];
    #pragma unroll
    for (int o2 = 0; o2 < 4; ++o2){
      v2f b2; b2.x = bb[2*o2]; b2.y = bb[2*o2+1];
      a2[o2][0]=b2; a2[o2][1]=b2; a2[o2][2]=b2; a2[o2][3]=b2;
    }
    #pragma unroll 1
    for (int i = 0; i < 8; ++i){
      #pragma unroll
      for (int rt = 0; rt < 2; ++rt){
        const int p = rt ? pB : pA;
        const int ri = rt ? rB : rA;
        const float* rowp = tile + i*360 + ri*20 + 2*tx;
        float e0 = rowp[0], e1 = rowp[1], e2 = rowp[2], e3 = rowp[3];
        const v2f* wip2 = (const v2f*)(wb + (i*4+p)*32);   // [q][o], uniform
        #pragma unroll
        for (int o2 = 0; o2 < 4; ++o2){
          v2f W0 = wip2[o2],    W1 = wip2[4+o2];
          v2f W2 = wip2[8+o2],  W3 = wip2[12+o2];
          a2[o2][0] -= W1*e1; a2[o2][2] -= W1*e2;  // x even, q=1
          a2[o2][0] -= W3*e0; a2[o2][2] -= W3*e1;  // x even, q=3
          a2[o2][1] -= W0*e2; a2[o2][3] -= W0*e3;  // x odd,  q=0
          a2[o2][1] -= W2*e1; a2[o2][3] -= W2*e2;  // x odd,  q=2
        }
      }
    }
    float lm[8];
    #pragma unroll
    for (int o = 0; o < 8; ++o){
      const int o2 = o >> 1;
      float b0v = (o&1) ? a2[o2][0].y : a2[o2][0].x;
      float b1v = (o&1) ? a2[o2][1].y : a2[o2][1].x;
      float b2v = (o&1) ? a2[o2][2].y : a2[o2][2].x;
      float b3v = (o&1) ? a2[o2][3].y : a2[o2][3].x;
      float v = fminf(fminf(fabsf(b0v),fabsf(b1v)),
                      fminf(fabsf(b2v),fabsf(b3v)));
      #pragma unroll
      for (int off = 32; off > 0; off >>= 1) v = fminf(v, __shfl_xor(v, off));
      lm[o] = v;
      *(float4*)(T + ((size_t)(bl*8+o))*HWo + (Y0+row)*Ho + X0 + 4*tx) =
          make_float4(b0v,b1v,b2v,b3v);
    }
    if ((threadIdx.x & 63) == 0){
      #pragma unroll
      for (int o = 0; o < 8; ++o)
        atomicMin(mn + maps + bl*8 + o, __float_as_uint(lm[o]));
    }
    return;
  }

  {
    // --- 3x3 conv (pad 1), FOUR phases of 2 ch, register-prefetch pipeline ---
    float* tile = smem;                       // 2*34*36 = 2448
    const int idx = bid - g2;
    const int tiles = tprR*tprR;
    const int bl = idx / tiles;
    const int t  = idx - bl*tiles;
    const int Y0 = (t/tprR)*32, X0 = (t - (t/tprR)*tprR)*32;
    const int bg = b0 + bl;
    const float* wb = wr + (size_t)(s*64+bg)*576;
    const float* bb = br + (s*64+bg)*8;
    const int HW = H*H;
    const float* xb = X + (size_t)bl*8*HW;
    const int tx = threadIdx.x & 7, ty = threadIdx.x >> 3;
    const bool act = (Y0+ty < H) && (X0+4*tx < H);  // only false when H==16
    v2f a2[4][4];
    #pragma unroll
    for (int o2 = 0; o2 < 4; ++o2){
      v2f b2; b2.x = bb[2*o2]; b2.y = bb[2*o2+1];
      a2[o2][0]=b2; a2[o2][1]=b2; a2[o2][2]=b2; a2[o2][3]=b2;
    }
    float pre[10];
    #pragma unroll
    for (int k = 0; k < 10; ++k){
      int e = threadIdx.x + k*BLK;
      float v = 0.f;
      if (e < 2448){
        int cc = e % 36; int rr = (e/36) % 34; int c2 = e/(36*34);
        int gy = Y0 - 1 + rr, gx = X0 - 1 + cc;
        if (cc < 34 && (unsigned)gy < (unsigned)H && (unsigned)gx < (unsigned)H)
          v = xb[(size_t)c2*HW + gy*H + gx];
      }
      pre[k] = v;
    }
    #pragma unroll 1
    for (int ph = 0; ph < 4; ++ph){
      if (ph > 0) __syncthreads();
      #pragma unroll
      for (int k = 0; k < 10; ++k){
        int e = threadIdx.x + k*BLK;
        if (e < 2448) tile[e] = pre[k];
      }
      __syncthreads();
      if (ph < 3){
        #pragma unroll
        for (int k = 0; k < 10; ++k){
          int e = threadIdx.x + k*BLK;
          float v = 0.f;
          if (e < 2448){
            int cc = e % 36; int rr = (e/36) % 34; int c2 = e/(36*34);
            int gy = Y0 - 1 + rr, gx = X0 - 1 + cc;
            if (cc < 34 && (unsigned)gy < (unsigned)H && (unsigned)gx < (unsigned)H)
              v = xb[(size_t)((ph+1)*2 + c2)*HW + gy*H + gx];
          }
          pre[k] = v;
        }
      }
      #pragma unroll 1
      for (int i = 0; i < 2; ++i){
        const float* tch = tile + i*1224;
        const int ig = ph*2 + i;
        #pragma unroll
        for (int p = 0; p < 3; ++p){
          const float* row = tch + (ty+p)*36 + 4*tx;
          float4 c0 = *(const float4*)row;
          float4 c1 = *(const float4*)(row+4);
          float c[8] = {c0.x,c0.y,c0.z,c0.w,c1.x,c1.y,c1.z,c1.w};
          const v2f* wip2 = (const v2f*)(wb + (ig*3+p)*24);
          #pragma unroll
          for (int q = 0; q < 3; ++q){
            #pragma unroll
            for (int o2 = 0; o2 < 4; ++o2){
              v2f w2 = wip2[q*4+o2];
              a2[o2][0] += w2*c[q];   a2[o2][1] += w2*c[q+1];
              a2[o2][2] += w2*c[q+2]; a2[o2][3] += w2*c[q+3];
            }
          }
        }
      }
    }
    float lm[8];
    #pragma unroll
    for (int o = 0; o < 8; ++o){
      const int o2 = o >> 1;
      float b0v = (o&1) ? a2[o2][0].y : a2[o2][0].x;
      float b1v = (o&1) ? a2[o2][1].y : a2[o2][1].x;
      float b2v = (o&1) ? a2[o2][2].y : a2[o2][2].x;
      float b3v = (o&1) ? a2[o2][3].y : a2[o2][3].x;
      float v = act ? fminf(fminf(fabsf(b0v),fabsf(b1v)),
                            fminf(fabsf(b2v),fabsf(b3v))) : 3.4e38f;
      #pragma unroll
      for (int off = 32; off > 0; off >>= 1) v = fminf(v, __shfl_xor(v, off));
      lm[o] = v;
      if (act){
        *(float4*)(D + ((size_t)(bl*8+o))*HW + (Y0+ty)*H + X0 + 4*tx) =
            make_float4(b0v,b1v,b2v,b3v);
      }
    }
    if ((threadIdx.x & 63) == 0){
      #pragma unroll
      for (int o = 0; o < 8; ++o) atomicMin(mn + bl*8 + o, __float_as_uint(lm[o]));
    }
  }
}

// s<3: next_x = (dln(Dr)[nearest-up] + dln(Dt)) * dln(Dm), into X. Quarter-px threads.
__global__ void combine_kernel(const float* __restrict__ dr, const float* __restrict__ dt,
                               const float* __restrict__ dm,
                               const unsigned* __restrict__ mn, int maps,
                               float* __restrict__ outx, int H, int total){
  int Ho = 2*H, HWo = Ho*Ho, HW = H*H;
  for (int e = blockIdx.x*blockDim.x + threadIdx.x; e < total; e += gridDim.x*blockDim.x){
    int m = e / HW;
    int qpx = e - m*HW;
    int qy = qpx / H, qx = qpx - qy*H;
    float mr = __uint_as_float(mn[m]);
    float mt = __uint_as_float(mn[maps + m]);
    float mm = __uint_as_float(mn[2*maps + m]);
    float r = dln_one(dr[(size_t)m*HW + qpx], mr);
    #pragma unroll
    for (int dy = 0; dy < 2; ++dy){
      size_t base = (size_t)m*HWo + (2*qy+dy)*Ho + 2*qx;
      float2 tv = *(const float2*)(dt + base);
      float2 mv = *(const float2*)(dm + base);
      float2 ov;
      ov.x = (r + dln_one(tv.x, mt)) * dln_one(mv.x, mm);
      ov.y = (r + dln_one(tv.y, mt)) * dln_one(mv.y, mm);
      *(float2*)(outx + base) = ov;
    }
  }
}

// s==3: combine + final dynamic 1x1 conv (8->3 ch) fused, writes d_out.
__global__ void combineF_kernel(const float* __restrict__ dr, const float* __restrict__ dt,
                                const float* __restrict__ dm,
                                const unsigned* __restrict__ mn, int maps,
                                const float* __restrict__ wo, const float* __restrict__ bo,
                                float* __restrict__ out, int b0, int total){
  for (int e = blockIdx.x*blockDim.x + threadIdx.x; e < total; e += gridDim.x*blockDim.x){
    int bl = e >> 14;
    int qpx = e & 16383;
    int qy = qpx >> 7, qx = qpx & 127;
    int bg = b0 + bl;
    float r[8], mtv[8], mmv[8];
    #pragma unroll
    for (int o = 0; o < 8; ++o){
      int m = bl*8 + o;
      float mr = __uint_as_float(mn[m]);
      mtv[o] = __uint_as_float(mn[maps + m]);
      mmv[o] = __uint_as_float(mn[2*maps + m]);
      r[o] = dln_one(dr[(size_t)m*16384 + qpx], mr);
    }
    #pragma unroll
    for (int dy = 0; dy < 2; ++dy){
      int y = 2*qy + dy, xx = 2*qx;
      float2 acc[3];
      #pragma unroll
      for (int of = 0; of < 3; ++of){
        float b = bo[bg*3 + of];
        acc[of].x = b; acc[of].y = b;
      }
      #pragma unroll
      for (int o = 0; o < 8; ++o){
        size_t base = (size_t)(bl*8+o)*65536 + y*256 + xx;
        float2 tv = *(const float2*)(dt + base);
        float2 mv = *(const float2*)(dm + base);
        float vx = (r[o] + dln_one(tv.x, mtv[o])) * dln_one(mv.x, mmv[o]);
        float vy = (r[o] + dln_one(tv.y, mtv[o])) * dln_one(mv.y, mmv[o]);
        #pragma unroll
        for (int of = 0; of < 3; ++of){
          float w = wo[bg*24 + of*8 + o];
          acc[of].x += w*vx; acc[of].y += w*vy;
        }
      }
      #pragma unroll
      for (int of = 0; of < 3; ++of){
        *(float2*)(out + ((size_t)(bg*3 + of))*65536 + y*256 + xx) = acc[of];
      }
    }
  }
}

static inline int grid_for(long long total){
  long long g = (total + BLK - 1) / BLK;
  if (g > 16384) g = 16384;
  if (g < 1) g = 1;
  return (int)g;
}

extern "C" void kernel_launch(void* const* d_in, const int* in_sizes, int n_in,
                              void* d_out, int out_size, void* d_ws, size_t ws_size,
                              hipStream_t stream){
  (void)in_sizes; (void)n_in; (void)out_size;
  const int*   ids   = (const int*)d_in[0];
  const float* cache = (const float*)d_in[1];
  const float* lat   = (const float*)d_in[2];
  const float* Wr = (const float*)d_in[3];
  const float* Ur = (const float*)d_in[4];
  const float* Vr = (const float*)d_in[5];
  const float* Br = (const float*)d_in[6];
  const float* Wt = (const float*)d_in[7];
  const float* Ut = (const float*)d_in[8];
  const float* Vt = (const float*)d_in[9];
  const float* Bt = (const float*)d_in[10];
  const float* Wm = (const float*)d_in[11];
  const float* Um = (const float*)d_in[12];
  const float* Vm = (const float*)d_in[13];
  const float* Bm = (const float*)d_in[14];
  const float* Wo = (const float*)d_in[15];
  const float* Uo = (const float*)d_in[16];
  const float* Vo = (const float*)d_in[17];
  const float* Bo = (const float*)d_in[18];
  float* out = (float*)d_out;
  float* ws  = (float*)d_ws;

  size_t off = 0;
  auto alloc = [&](size_t n){ size_t o = off; off += n; return o; };
  size_t o_ctx = alloc(2048);
  size_t o_ur = alloc(4*64*128),  o_vr = alloc(4*64*1152);
  size_t o_ut = alloc(4*64*128),  o_vt = alloc(4*64*2048);
  size_t o_um = alloc(4*64*128),  o_vm = alloc(4*64*3200);
  size_t o_br = alloc(4*64*8), o_bt = alloc(4*64*8), o_bm = alloc(4*64*8);
  size_t o_uo = alloc(64*48), o_vo = alloc(64*128), o_bo = alloc(64*3);
  size_t o_wr = alloc(4*64*8*72), o_wt = alloc(4*64*8*128), o_wm = alloc(4*64*8*200);
  size_t o_wo = alloc(64*24);
  size_t o_mn = alloc(4*3*512);          // [stage][3][maps]
  size_t small_end = off;

  // per sample: X (8*128^2) + D (8*128^2) + T (8*256^2) + M (8*256^2)
  const size_t perS = 2*(size_t)131072 + 2*(size_t)524288;
  size_t ws_f = ws_size / sizeof(float);
  int nb = 64;
  while (nb > 1 && small_end + (size_t)nb*perS > ws_f) nb >>= 1;

  size_t o_X = small_end;
  size_t o_D = o_X + (size_t)nb*131072;
  size_t o_T = o_D + (size_t)nb*131072;
  size_t o_M = o_T + (size_t)nb*524288;
  unsigned* mn = (unsigned*)(ws + o_mn);

  gather_ctx_kernel<<<8, BLK, 0, stream>>>(ids, cache, ws + o_ctx);

  W1Args a1;
  a1.M[0]=Ur;  a1.out[0]=ws+o_ur;
  a1.M[1]=Vr;  a1.out[1]=ws+o_vr;
  a1.M[2]=Ut;  a1.out[2]=ws+o_ut;
  a1.M[3]=Vt;  a1.out[3]=ws+o_vt;
  a1.M[4]=Um;  a1.out[4]=ws+o_um;
  a1.M[5]=Vm;  a1.out[5]=ws+o_vm;
  a1.M[6]=Br;  a1.out[6]=ws+o_br;
  a1.M[7]=Bt;  a1.out[7]=ws+o_bt;
  a1.M[8]=Bm;  a1.out[8]=ws+o_bm;
  a1.M[9]=Uo;  a1.out[9]=ws+o_uo;
  a1.M[10]=Vo; a1.out[10]=ws+o_vo;
  a1.M[11]=Bo; a1.out[11]=ws+o_bo;
  w1_kernel<<<256, BLK, 0, stream>>>(ws + o_ctx, a1);

  W2Args a2;
  a2.W[0]=Wr; a2.u[0]=ws+o_ur; a2.v[0]=ws+o_vr; a2.out[0]=ws+o_wr;
  a2.W[1]=Wt; a2.u[1]=ws+o_ut; a2.v[1]=ws+o_vt; a2.out[1]=ws+o_wt;
  a2.W[2]=Wm; a2.u[2]=ws+o_um; a2.v[2]=ws+o_vm; a2.out[2]=ws+o_wm;
  a2.W[3]=Wo; a2.u[3]=ws+o_uo; a2.v[3]=ws+o_vo; a2.out[3]=ws+o_wo;
  w2_kernel<<<256, BLK, 0, stream>>>(a2);

  for (int b0 = 0; b0 < 64; b0 += nb){
    gather_x_kernel<<<grid_for((long long)nb*2048), BLK, 0, stream>>>(
        ids, lat, ws+o_X, b0, nb);
    int maps = nb*8;
    init_min_kernel<<<(4*3*maps + BLK-1)/BLK, BLK, 0, stream>>>(mn, 4*3*maps);
    int H = 16;
    for (int s = 0; s < 4; ++s){
      int Ho = 2*H;
      int tprR = (H >= 32) ? H/32 : 1;
      int tprO = Ho/32;
      int gR = nb*tprR*tprR;
      int gT = nb*tprO*tprO;
      int gM = nb*tprO*tprO;
      int g1 = gM, g2 = gM + gT;              // convm first, then convt, convr
      unsigned* mns = mn + (size_t)s*3*maps;
      conv3_fused<<<gM+gT+gR, BLK, 0, stream>>>(
          ws+o_X, ws+o_wr, ws+o_br, ws+o_wt, ws+o_bt, ws+o_wm, ws+o_bm,
          ws+o_D, ws+o_T, ws+o_M, mns, maps, H, b0, s, tprR, tprO, g1, g2);
      if (s < 3){
        long long totalq = (long long)maps*H*H;
        combine_kernel<<<grid_for(totalq), BLK, 0, stream>>>(
            ws+o_D, ws+o_T, ws+o_M, mns, maps, ws+o_X, H, (int)totalq);
      } else {
        long long totalf = (long long)nb*16384;
        combineF_kernel<<<grid_for(totalf), BLK, 0, stream>>>(
            ws+o_D, ws+o_T, ws+o_M, mns, maps, ws+o_wo, ws+o_bo, out, b0, (int)totalf);
      }
      H = Ho;
    }
  }
}

// Round 16
// 815.606 us; speedup vs baseline: 1.5621x; 1.3617x over previous
//
#include <hip/hip_runtime.h>
#include <math.h>

// ExperimentalModel_1752346656819: 4-stage dynamic-conv decoder, fp32 compute.
// R15: conv intermediate buffers D/T/M stored as bf16 (RNE) — halves their
// write+read traffic and drops per-sample ws 5.25->2.75 MB (chunker may fit
// all 64 samples in one pass). Mins stay fp32 (pre-rounding). X stays fp32.
// Structure otherwise = R14 (prefetch pipeline, longest-first grid).

#define BLK 256
#define EF 2.7182818284590452f

typedef float v2f __attribute__((ext_vector_type(2)));

struct W1Args { const float* M[12]; float* out[12]; };
struct W2Args { const float* W[4]; const float* u[4]; const float* v[4]; float* out[4]; };

__device__ __forceinline__ unsigned short f2b(float f){
  unsigned u = __float_as_uint(f);
  unsigned r = u + 0x7FFFu + ((u >> 16) & 1u);   // round-to-nearest-even
  return (unsigned short)(r >> 16);
}
__device__ __forceinline__ float b2f(unsigned short h){
  return __uint_as_float((unsigned)h << 16);
}

__device__ __forceinline__ float dln_one(float y, float m){
  float a = fabsf(y) - m;
  float v = __logf(__logf(a + EF) + 0.01f);
  return (y > 0.0f) ? v : -v;
}

__global__ void gather_ctx_kernel(const int* __restrict__ ids,
                                  const float* __restrict__ cache,
                                  float* __restrict__ ctx){
  int e = blockIdx.x*blockDim.x + threadIdx.x;
  if (e < 64*32){
    int b = e >> 5, l = e & 31;
    ctx[e] = cache[(size_t)ids[b]*32 + l];
  }
}

__global__ void gather_x_kernel(const int* __restrict__ ids,
                                const float* __restrict__ lat,
                                float* __restrict__ X, int b0, int nb){
  int total = nb*2048;
  int e = blockIdx.x*blockDim.x + threadIdx.x;
  if (e < total){
    int bl = e >> 11;
    int r  = e & 2047;
    X[e] = lat[(size_t)ids[b0+bl]*2048 + r];
  }
}

__global__ void w1_kernel(const float* __restrict__ ctx, W1Args args){
  const int S[12] = {4,4,4,4,4,4,4,4,4,1,1,1};
  const int K[12] = {128,1152,128,2048,128,3200,8,8,8,48,128,3};
  int tid = blockIdx.x*blockDim.x + threadIdx.x;
  int nth = gridDim.x*blockDim.x;
  for (int seg = 0; seg < 12; ++seg){
    const float* M = args.M[seg];
    float* out = args.out[seg];
    int Ks = K[seg];
    int total = S[seg]*64*Ks;
    for (int e = tid; e < total; e += nth){
      int k = e % Ks;
      int b = (e / Ks) % 64;
      int s = e / (Ks*64);
      const float* Ms = M + (size_t)s*32*Ks + k;
      const float* cb = ctx + b*32;
      float acc = 0.f;
      #pragma unroll
      for (int l = 0; l < 32; ++l) acc += cb[l]*Ms[(size_t)l*Ks];
      out[e] = acc;
    }
  }
}

// Dynamic weights. Segs 0-2 TRANSPOSED to [s][b][i][p][q][o]; seg 3 [b][o][i].
__global__ void w2_kernel(W2Args args){
  const int S[4] = {4,4,4,1};
  const int O[4] = {8,8,8,3};
  const int K[4] = {72,128,200,8};
  const int KH[4] = {3,4,5,1};
  int tid = blockIdx.x*blockDim.x + threadIdx.x;
  int nth = gridDim.x*blockDim.x;
  for (int seg = 0; seg < 4; ++seg){
    int Os = O[seg], Ks = K[seg];
    int kh = KH[seg], kk = kh*kh;
    int total = S[seg]*64*Os*Ks;
    const float* Wt = args.W[seg];
    const float* u = args.u[seg];
    const float* v = args.v[seg];
    float* out = args.out[seg];
    for (int e = tid; e < total; e += nth){
      int k = e % Ks;
      int o = (e/Ks) % Os;
      int b = (e/(Ks*Os)) % 64;
      int s = e/(Ks*Os*64);
      const float* us = u + (size_t)(s*64+b)*16*Os;
      const float* vs = v + (size_t)(s*64+b)*16*Ks;
      float mod = 0.f;
      #pragma unroll
      for (int r = 0; r < 16; ++r) mod += us[r*Os+o]*vs[r*Ks+k];
      float val = Wt[(size_t)(s*Os+o)*Ks + k] * (1.0f + mod + 1e-3f);
      size_t dst;
      if (seg < 3){
        int i = k / kk, r2 = k - i*kk, p = r2 / kh, q = r2 - p*kh;
        dst = (size_t)(s*64+b)*(8*Ks) + (size_t)(((i*kh+p)*kh+q)*8 + o);
      } else {
        dst = (size_t)b*24 + o*8 + k;
      }
      out[dst] = val;
    }
  }
}

__global__ void init_min_kernel(unsigned* __restrict__ mn, int n){
  int e = blockIdx.x*blockDim.x + threadIdx.x;
  if (e < n) mn[e] = 0x7F800000u;   // +inf
}

// Fused per-stage conv kernel, LONGEST-FIRST order:
// blocks [0,g1) = convm (5x5 on bilinear-up(log)); [g1,g2) = convt (4x4 T);
// [g2,...) = convr (3x3). Outputs D/T/M in bf16. LDS union 15.5 KB.
__global__ void __launch_bounds__(BLK) conv3_fused(
    const float* __restrict__ X,
    const float* __restrict__ wr, const float* __restrict__ br,
    const float* __restrict__ wt, const float* __restrict__ bt,
    const float* __restrict__ wm, const float* __restrict__ bm,
    unsigned short* __restrict__ D, unsigned short* __restrict__ T,
    unsigned short* __restrict__ M,
    unsigned* __restrict__ mn, int maps, int H, int b0, int s,
    int tprR, int tprO, int g1, int g2){
  __shared__ __align__(16) float smem[3880];
  const int bid = blockIdx.x;

  if (bid < g1){
    // --- convm: 5x5 (pad 2) on bilinear-up(log(|X|+1)); 4 phases of 2 ch,
    //     register-prefetch pipeline on quarter-res halo loads ---
    float* tile = smem;                       // 2*36*40 = 2880
    float* lbuf = smem + 2880;                // 2*20*25 = 1000
    const int idx = bid;
    const int tiles = tprO*tprO;
    const int bl = idx / tiles;
    const int t  = idx - bl*tiles;
    const int Y0 = (t/tprO)*32, X0 = (t - (t/tprO)*tprO)*32;
    const int bg = b0 + bl;
    const float* wb = wm + (size_t)(s*64+bg)*1600;
    const float* bb = bm + (s*64+bg)*8;
    const int Hi = 2*H;
    const int Hq = H, HWq = Hq*Hq;
    const int HW = Hi*Hi;
    const float* xb = X + (size_t)bl*8*HWq;
    const int LY0 = ((Y0-2)>>1) - 1;
    const int LX0 = ((X0-2)>>1) - 1;
    const int tx = threadIdx.x & 7, ty = threadIdx.x >> 3;
    v2f a2[4][4];
    #pragma unroll
    for (int o2 = 0; o2 < 4; ++o2){
      v2f b2; b2.x = bb[2*o2]; b2.y = bb[2*o2+1];
      a2[o2][0]=b2; a2[o2][1]=b2; a2[o2][2]=b2; a2[o2][3]=b2;
    }
    float pre[4];
    #pragma unroll
    for (int k = 0; k < 4; ++k){
      int e = threadIdx.x + k*BLK;
      float v = 0.f;
      if (e < 1000){
        int c2 = e/500; int r2 = e - c2*500; int rr = r2/25; int cc = r2 - rr*25;
        int ly = LY0 + rr, lx = LX0 + cc;
        if (cc < 22 && (unsigned)ly < (unsigned)Hq && (unsigned)lx < (unsigned)Hq)
          v = xb[(size_t)c2*HWq + ly*Hq + lx];
      }
      pre[k] = v;
    }
    #pragma unroll 1
    for (int ph = 0; ph < 4; ++ph){
      if (ph > 0) __syncthreads();
      #pragma unroll
      for (int k = 0; k < 4; ++k){
        int e = threadIdx.x + k*BLK;
        if (e < 1000) lbuf[e] = __logf(fabsf(pre[k]) + 1.0f);
      }
      __syncthreads();
      if (ph < 3){
        #pragma unroll
        for (int k = 0; k < 4; ++k){
          int e = threadIdx.x + k*BLK;
          float v = 0.f;
          if (e < 1000){
            int c2 = e/500; int r2 = e - c2*500; int rr = r2/25; int cc = r2 - rr*25;
            int ly = LY0 + rr, lx = LX0 + cc;
            if (cc < 22 && (unsigned)ly < (unsigned)Hq && (unsigned)lx < (unsigned)Hq)
              v = xb[(size_t)((ph+1)*2 + c2)*HWq + ly*Hq + lx];
          }
          pre[k] = v;
        }
      }
      // expand 2x bilinear (half-pixel, edge clamp) into 36x40 halo tile
      #pragma unroll 1
      for (int e = threadIdx.x; e < 2880; e += BLK){
        int c2 = e/1440; int r2 = e - c2*1440; int rr = r2/40; int cc = r2 - rr*40;
        int gy = Y0 - 2 + rr, gx = X0 - 2 + cc;
        float f = 0.f;
        if (cc < 36 && (unsigned)gy < (unsigned)Hi && (unsigned)gx < (unsigned)Hi){
          int jy = gy >> 1;
          int ny = (gy & 1) ? ((jy+1 < Hq) ? jy+1 : Hq-1) : ((jy > 0) ? jy-1 : 0);
          int jx = gx >> 1;
          int nx = (gx & 1) ? ((jx+1 < Hq) ? jx+1 : Hq-1) : ((jx > 0) ? jx-1 : 0);
          const float* lb = lbuf + c2*500;
          float f00 = lb[(jy-LY0)*25 + (jx-LX0)];
          float f01 = lb[(jy-LY0)*25 + (nx-LX0)];
          float f10 = lb[(ny-LY0)*25 + (jx-LX0)];
          float f11 = lb[(ny-LY0)*25 + (nx-LX0)];
          f = 0.5625f*f00 + 0.1875f*(f01 + f10) + 0.0625f*f11;
        }
        tile[e] = f;
      }
      __syncthreads();
      #pragma unroll 1
      for (int i = 0; i < 2; ++i){
        const float* tch = tile + i*1440;
        const int ig = ph*2 + i;
        #pragma unroll
        for (int p = 0; p < 5; ++p){
          const float* row = tch + (ty+p)*40 + 4*tx;
          float4 c0 = *(const float4*)row;
          float4 c1 = *(const float4*)(row+4);
          float c[8] = {c0.x,c0.y,c0.z,c0.w,c1.x,c1.y,c1.z,c1.w};
          const v2f* wip2 = (const v2f*)(wb + (ig*5+p)*40);   // [q][o], uniform
          #pragma unroll
          for (int q = 0; q < 5; ++q){
            #pragma unroll
            for (int o2 = 0; o2 < 4; ++o2){
              v2f w2 = wip2[q*4+o2];
              a2[o2][0] += w2*c[q];   a2[o2][1] += w2*c[q+1];
              a2[o2][2] += w2*c[q+2]; a2[o2][3] += w2*c[q+3];
            }
          }
        }
      }
    }
    float lm[8];
    #pragma unroll
    for (int o = 0; o < 8; ++o){
      const int o2 = o >> 1;
      float b0v = (o&1) ? a2[o2][0].y : a2[o2][0].x;
      float b1v = (o&1) ? a2[o2][1].y : a2[o2][1].x;
      float b2v = (o&1) ? a2[o2][2].y : a2[o2][2].x;
      float b3v = (o&1) ? a2[o2][3].y : a2[o2][3].x;
      float v = fminf(fminf(fabsf(b0v),fabsf(b1v)),
                      fminf(fabsf(b2v),fabsf(b3v)));
      #pragma unroll
      for (int off = 32; off > 0; off >>= 1) v = fminf(v, __shfl_xor(v, off));
      lm[o] = v;
      ushort4 h4 = make_ushort4(f2b(b0v), f2b(b1v), f2b(b2v), f2b(b3v));
      *(ushort4*)(M + ((size_t)(bl*8+o))*HW + (Y0+ty)*Hi + X0 + 4*tx) = h4;
    }
    if ((threadIdx.x & 63) == 0){
      #pragma unroll
      for (int o = 0; o < 8; ++o)
        atomicMin(mn + 2*maps + bl*8 + o, __float_as_uint(lm[o]));
    }
    return;
  }

  if (bid < g2){
    // ------- convt: 4x4 stride-2 transposed conv of (-x) (pad 1) -------
    float* tile = smem;                       // 8*18*20 = 2880
    const int idx = bid - g1;
    const int tiles = tprO*tprO;
    const int bl = idx / tiles;
    const int t  = idx - bl*tiles;
    const int Y0 = (t/tprO)*32, X0 = (t - (t/tprO)*tprO)*32;  // output coords
    const int bg = b0 + bl;
    const float* wb = wt + (size_t)(s*64+bg)*1024;
    const float* bb = bt + (s*64+bg)*8;
    const int Ho = 2*H, HWo = Ho*Ho, HW = H*H;
    const float* xb = X + (size_t)bl*8*HW;
    const int ry0 = Y0/2 - 1, rx0 = X0/2 - 1;
    {
      float vb[12];
      #pragma unroll
      for (int k = 0; k < 12; ++k){
        int e = threadIdx.x + k*BLK;
        float v = 0.f;
        if (e < 2880){
          int cc = e % 20; int rr = (e/20) % 18; int ch = e/(20*18);
          int gy = ry0 + rr, gx = rx0 + cc;
          if (cc < 18 && (unsigned)gy < (unsigned)H && (unsigned)gx < (unsigned)H)
            v = xb[(size_t)ch*HW + gy*H + gx];
        }
        vb[k] = v;
      }
      #pragma unroll
      for (int k = 0; k < 12; ++k){
        int e = threadIdx.x + k*BLK;
        if (e < 2880) tile[e] = vb[k];
      }
    }
    __syncthreads();
    const int tx = threadIdx.x & 7;
    const int ty2 = threadIdx.x >> 3;
    const int row = (ty2 < 16) ? 2*ty2 : 2*(ty2-16)+1;   // wave-parity-uniform
    const int yodd = __builtin_amdgcn_readfirstlane(row & 1);
    const int half = row >> 1;
    const int pA = yodd ? 0 : 1, rA = yodd ? half+2 : half+1;
    const int pB = yodd ? 2 : 3, rB = yodd ? half+1 : half;
    v2f a2[4][4];
    #pragma unroll
    for (int o2 = 0; o2 < 4; ++o2){
      v2f b2; b2.x = bb[2*o2]; b2.y = bb[2*o2+1];
      a2[o2][0]=b2; a2[o2][1]=b2; a2[o2][2]=b2; a2[o2][3]=b2;
    }
    #pragma unroll 1
    for (int i = 0; i < 8; ++i){
      #pragma unroll
      for (int rt = 0; rt < 2; ++rt){
        const int p = rt ? pB : pA;
        const int ri = rt ? rB : rA;
        const float* rowp = tile + i*360 + ri*20 + 2*tx;
        float e0 = rowp[0], e1 = rowp[1], e2 = rowp[2], e3 = rowp[3];
        const v2f* wip2 = (const v2f*)(wb + (i*4+p)*32);   // [q][o], uniform
        #pragma unroll
        for (int o2 = 0; o2 < 4; ++o2){
          v2f W0 = wip2[o2],    W1 = wip2[4+o2];
          v2f W2 = wip2[8+o2],  W3 = wip2[12+o2];
          a2[o2][0] -= W1*e1; a2[o2][2] -= W1*e2;  // x even, q=1
          a2[o2][0] -= W3*e0; a2[o2][2] -= W3*e1;  // x even, q=3
          a2[o2][1] -= W0*e2; a2[o2][3] -= W0*e3;  // x odd,  q=0
          a2[o2][1] -= W2*e1; a2[o2][3] -= W2*e2;  // x odd,  q=2
        }
      }
    }
    float lm[8];
    #pragma unroll
    for (int o = 0; o < 8; ++o){
      const int o2 = o >> 1;
      float b0v = (o&1) ? a2[o2][0].y : a2[o2][0].x;
      float b1v = (o&1) ? a2[o2][1].y : a2[o2][1].x;
      float b2v = (o&1) ? a2[o2][2].y : a2[o2][2].x;
      float b3v = (o&1) ? a2[o2][3].y : a2[o2][3].x;
      float v = fminf(fminf(fabsf(b0v),fabsf(b1v)),
                      fminf(fabsf(b2v),fabsf(b3v)));
      #pragma unroll
      for (int off = 32; off > 0; off >>= 1) v = fminf(v, __shfl_xor(v, off));
      lm[o] = v;
      ushort4 h4 = make_ushort4(f2b(b0v), f2b(b1v), f2b(b2v), f2b(b3v));
      *(ushort4*)(T + ((size_t)(bl*8+o))*HWo + (Y0+row)*Ho + X0 + 4*tx) = h4;
    }
    if ((threadIdx.x & 63) == 0){
      #pragma unroll
      for (int o = 0; o < 8; ++o)
        atomicMin(mn + maps + bl*8 + o, __float_as_uint(lm[o]));
    }
    return;
  }

  {
    // --- convr: 3x3 (pad 1), FOUR phases of 2 ch, register-prefetch pipeline ---
    float* tile = smem;                       // 2*34*36 = 2448
    const int idx = bid - g2;
    const int tiles = tprR*tprR;
    const int bl = idx / tiles;
    const int t  = idx - bl*tiles;
    const int Y0 = (t/tprR)*32, X0 = (t - (t/tprR)*tprR)*32;
    const int bg = b0 + bl;
    const float* wb = wr + (size_t)(s*64+bg)*576;
    const float* bb = br + (s*64+bg)*8;
    const int HW = H*H;
    const float* xb = X + (size_t)bl*8*HW;
    const int tx = threadIdx.x & 7, ty = threadIdx.x >> 3;
    const bool act = (Y0+ty < H) && (X0+4*tx < H);  // only false when H==16
    v2f a2[4][4];
    #pragma unroll
    for (int o2 = 0; o2 < 4; ++o2){
      v2f b2; b2.x = bb[2*o2]; b2.y = bb[2*o2+1];
      a2[o2][0]=b2; a2[o2][1]=b2; a2[o2][2]=b2; a2[o2][3]=b2;
    }
    float pre[10];
    #pragma unroll
    for (int k = 0; k < 10; ++k){
      int e = threadIdx.x + k*BLK;
      float v = 0.f;
      if (e < 2448){
        int cc = e % 36; int rr = (e/36) % 34; int c2 = e/(36*34);
        int gy = Y0 - 1 + rr, gx = X0 - 1 + cc;
        if (cc < 34 && (unsigned)gy < (unsigned)H && (unsigned)gx < (unsigned)H)
          v = xb[(size_t)c2*HW + gy*H + gx];
      }
      pre[k] = v;
    }
    #pragma unroll 1
    for (int ph = 0; ph < 4; ++ph){
      if (ph > 0) __syncthreads();
      #pragma unroll
      for (int k = 0; k < 10; ++k){
        int e = threadIdx.x + k*BLK;
        if (e < 2448) tile[e] = pre[k];
      }
      __syncthreads();
      if (ph < 3){
        #pragma unroll
        for (int k = 0; k < 10; ++k){
          int e = threadIdx.x + k*BLK;
          float v = 0.f;
          if (e < 2448){
            int cc = e % 36; int rr = (e/36) % 34; int c2 = e/(36*34);
            int gy = Y0 - 1 + rr, gx = X0 - 1 + cc;
            if (cc < 34 && (unsigned)gy < (unsigned)H && (unsigned)gx < (unsigned)H)
              v = xb[(size_t)((ph+1)*2 + c2)*HW + gy*H + gx];
          }
          pre[k] = v;
        }
      }
      #pragma unroll 1
      for (int i = 0; i < 2; ++i){
        const float* tch = tile + i*1224;
        const int ig = ph*2 + i;
        #pragma unroll
        for (int p = 0; p < 3; ++p){
          const float* row = tch + (ty+p)*36 + 4*tx;
          float4 c0 = *(const float4*)row;
          float4 c1 = *(const float4*)(row+4);
          float c[8] = {c0.x,c0.y,c0.z,c0.w,c1.x,c1.y,c1.z,c1.w};
          const v2f* wip2 = (const v2f*)(wb + (ig*3+p)*24);
          #pragma unroll
          for (int q = 0; q < 3; ++q){
            #pragma unroll
            for (int o2 = 0; o2 < 4; ++o2){
              v2f w2 = wip2[q*4+o2];
              a2[o2][0] += w2*c[q];   a2[o2][1] += w2*c[q+1];
              a2[o2][2] += w2*c[q+2]; a2[o2][3] += w2*c[q+3];
            }
          }
        }
      }
    }
    float lm[8];
    #pragma unroll
    for (int o = 0; o < 8; ++o){
      const int o2 = o >> 1;
      float b0v = (o&1) ? a2[o2][0].y : a2[o2][0].x;
      float b1v = (o&1) ? a2[o2][1].y : a2[o2][1].x;
      float b2v = (o&1) ? a2[o2][2].y : a2[o2][2].x;
      float b3v = (o&1) ? a2[o2][3].y : a2[o2][3].x;
      float v = act ? fminf(fminf(fabsf(b0v),fabsf(b1v)),
                            fminf(fabsf(b2v),fabsf(b3v))) : 3.4e38f;
      #pragma unroll
      for (int off = 32; off > 0; off >>= 1) v = fminf(v, __shfl_xor(v, off));
      lm[o] = v;
      if (act){
        ushort4 h4 = make_ushort4(f2b(b0v), f2b(b1v), f2b(b2v), f2b(b3v));
        *(ushort4*)(D + ((size_t)(bl*8+o))*HW + (Y0+ty)*H + X0 + 4*tx) = h4;
      }
    }
    if ((threadIdx.x & 63) == 0){
      #pragma unroll
      for (int o = 0; o < 8; ++o) atomicMin(mn + bl*8 + o, __float_as_uint(lm[o]));
    }
  }
}

// s<3: next_x = (dln(Dr)[nearest-up] + dln(Dt)) * dln(Dm), into X. Quarter-px threads.
__global__ void combine_kernel(const unsigned short* __restrict__ dr,
                               const unsigned short* __restrict__ dt,
                               const unsigned short* __restrict__ dm,
                               const unsigned* __restrict__ mn, int maps,
                               float* __restrict__ outx, int H, int total){
  int Ho = 2*H, HWo = Ho*Ho, HW = H*H;
  for (int e = blockIdx.x*blockDim.x + threadIdx.x; e < total; e += gridDim.x*blockDim.x){
    int m = e / HW;
    int qpx = e - m*HW;
    int qy = qpx / H, qx = qpx - qy*H;
    float mr = __uint_as_float(mn[m]);
    float mt = __uint_as_float(mn[maps + m]);
    float mm = __uint_as_float(mn[2*maps + m]);
    float r = dln_one(b2f(dr[(size_t)m*HW + qpx]), mr);
    #pragma unroll
    for (int dy = 0; dy < 2; ++dy){
      size_t base = (size_t)m*HWo + (2*qy+dy)*Ho + 2*qx;
      ushort2 tv = *(const ushort2*)(dt + base);
      ushort2 mv = *(const ushort2*)(dm + base);
      float2 ov;
      ov.x = (r + dln_one(b2f(tv.x), mt)) * dln_one(b2f(mv.x), mm);
      ov.y = (r + dln_one(b2f(tv.y), mt)) * dln_one(b2f(mv.y), mm);
      *(float2*)(outx + base) = ov;
    }
  }
}

// s==3: combine + final dynamic 1x1 conv (8->3 ch) fused, writes d_out.
__global__ void combineF_kernel(const unsigned short* __restrict__ dr,
                                const unsigned short* __restrict__ dt,
                                const unsigned short* __restrict__ dm,
                                const unsigned* __restrict__ mn, int maps,
                                const float* __restrict__ wo, const float* __restrict__ bo,
                                float* __restrict__ out, int b0, int total){
  for (int e = blockIdx.x*blockDim.x + threadIdx.x; e < total; e += gridDim.x*blockDim.x){
    int bl = e >> 14;
    int qpx = e & 16383;
    int qy = qpx >> 7, qx = qpx & 127;
    int bg = b0 + bl;
    float r[8], mtv[8], mmv[8];
    #pragma unroll
    for (int o = 0; o < 8; ++o){
      int m = bl*8 + o;
      float mr = __uint_as_float(mn[m]);
      mtv[o] = __uint_as_float(mn[maps + m]);
      mmv[o] = __uint_as_float(mn[2*maps + m]);
      r[o] = dln_one(b2f(dr[(size_t)m*16384 + qpx]), mr);
    }
    #pragma unroll
    for (int dy = 0; dy < 2; ++dy){
      int y = 2*qy + dy, xx = 2*qx;
      float2 acc[3];
      #pragma unroll
      for (int of = 0; of < 3; ++of){
        float b = bo[bg*3 + of];
        acc[of].x = b; acc[of].y = b;
      }
      #pragma unroll
      for (int o = 0; o < 8; ++o){
        size_t base = (size_t)(bl*8+o)*65536 + y*256 + xx;
        ushort2 tv = *(const ushort2*)(dt + base);
        ushort2 mv = *(const ushort2*)(dm + base);
        float vx = (r[o] + dln_one(b2f(tv.x), mtv[o])) * dln_one(b2f(mv.x), mmv[o]);
        float vy = (r[o] + dln_one(b2f(tv.y), mtv[o])) * dln_one(b2f(mv.y), mmv[o]);
        #pragma unroll
        for (int of = 0; of < 3; ++of){
          float w = wo[bg*24 + of*8 + o];
          acc[of].x += w*vx; acc[of].y += w*vy;
        }
      }
      #pragma unroll
      for (int of = 0; of < 3; ++of){
        *(float2*)(out + ((size_t)(bg*3 + of))*65536 + y*256 + xx) = acc[of];
      }
    }
  }
}

static inline int grid_for(long long total){
  long long g = (total + BLK - 1) / BLK;
  if (g > 16384) g = 16384;
  if (g < 1) g = 1;
  return (int)g;
}

extern "C" void kernel_launch(void* const* d_in, const int* in_sizes, int n_in,
                              void* d_out, int out_size, void* d_ws, size_t ws_size,
                              hipStream_t stream){
  (void)in_sizes; (void)n_in; (void)out_size;
  const int*   ids   = (const int*)d_in[0];
  const float* cache = (const float*)d_in[1];
  const float* lat   = (const float*)d_in[2];
  const float* Wr = (const float*)d_in[3];
  const float* Ur = (const float*)d_in[4];
  const float* Vr = (const float*)d_in[5];
  const float* Br = (const float*)d_in[6];
  const float* Wt = (const float*)d_in[7];
  const float* Ut = (const float*)d_in[8];
  const float* Vt = (const float*)d_in[9];
  const float* Bt = (const float*)d_in[10];
  const float* Wm = (const float*)d_in[11];
  const float* Um = (const float*)d_in[12];
  const float* Vm = (const float*)d_in[13];
  const float* Bm = (const float*)d_in[14];
  const float* Wo = (const float*)d_in[15];
  const float* Uo = (const float*)d_in[16];
  const float* Vo = (const float*)d_in[17];
  const float* Bo = (const float*)d_in[18];
  float* out = (float*)d_out;
  float* ws  = (float*)d_ws;

  size_t off = 0;
  auto alloc = [&](size_t n){ size_t o = off; off += n; return o; };
  size_t o_ctx = alloc(2048);
  size_t o_ur = alloc(4*64*128),  o_vr = alloc(4*64*1152);
  size_t o_ut = alloc(4*64*128),  o_vt = alloc(4*64*2048);
  size_t o_um = alloc(4*64*128),  o_vm = alloc(4*64*3200);
  size_t o_br = alloc(4*64*8), o_bt = alloc(4*64*8), o_bm = alloc(4*64*8);
  size_t o_uo = alloc(64*48), o_vo = alloc(64*128), o_bo = alloc(64*3);
  size_t o_wr = alloc(4*64*8*72), o_wt = alloc(4*64*8*128), o_wm = alloc(4*64*8*200);
  size_t o_wo = alloc(64*24);
  size_t o_mn = alloc(4*3*512);          // [stage][3][maps]
  size_t small_end = off;

  // per sample (float units): X 131072 + D 65536 (bf16) + T 262144 + M 262144
  const size_t perS = 131072 + 65536 + 262144 + 262144;
  size_t ws_f = ws_size / sizeof(float);
  int nb = 64;
  while (nb > 1 && small_end + (size_t)nb*perS > ws_f) nb >>= 1;

  size_t o_X = small_end;
  size_t o_D = o_X + (size_t)nb*131072;
  size_t o_T = o_D + (size_t)nb*65536;
  size_t o_M = o_T + (size_t)nb*262144;
  unsigned* mn = (unsigned*)(ws + o_mn);
  unsigned short* Db = (unsigned short*)(ws + o_D);
  unsigned short* Tb = (unsigned short*)(ws + o_T);
  unsigned short* Mb = (unsigned short*)(ws + o_M);

  gather_ctx_kernel<<<8, BLK, 0, stream>>>(ids, cache, ws + o_ctx);

  W1Args a1;
  a1.M[0]=Ur;  a1.out[0]=ws+o_ur;
  a1.M[1]=Vr;  a1.out[1]=ws+o_vr;
  a1.M[2]=Ut;  a1.out[2]=ws+o_ut;
  a1.M[3]=Vt;  a1.out[3]=ws+o_vt;
  a1.M[4]=Um;  a1.out[4]=ws+o_um;
  a1.M[5]=Vm;  a1.out[5]=ws+o_vm;
  a1.M[6]=Br;  a1.out[6]=ws+o_br;
  a1.M[7]=Bt;  a1.out[7]=ws+o_bt;
  a1.M[8]=Bm;  a1.out[8]=ws+o_bm;
  a1.M[9]=Uo;  a1.out[9]=ws+o_uo;
  a1.M[10]=Vo; a1.out[10]=ws+o_vo;
  a1.M[11]=Bo; a1.out[11]=ws+o_bo;
  w1_kernel<<<256, BLK, 0, stream>>>(ws + o_ctx, a1);

  W2Args a2;
  a2.W[0]=Wr; a2.u[0]=ws+o_ur; a2.v[0]=ws+o_vr; a2.out[0]=ws+o_wr;
  a2.W[1]=Wt; a2.u[1]=ws+o_ut; a2.v[1]=ws+o_vt; a2.out[1]=ws+o_wt;
  a2.W[2]=Wm; a2.u[2]=ws+o_um; a2.v[2]=ws+o_vm; a2.out[2]=ws+o_wm;
  a2.W[3]=Wo; a2.u[3]=ws+o_uo; a2.v[3]=ws+o_vo; a2.out[3]=ws+o_wo;
  w2_kernel<<<256, BLK, 0, stream>>>(a2);

  for (int b0 = 0; b0 < 64; b0 += nb){
    gather_x_kernel<<<grid_for((long long)nb*2048), BLK, 0, stream>>>(
        ids, lat, ws+o_X, b0, nb);
    int maps = nb*8;
    init_min_kernel<<<(4*3*maps + BLK-1)/BLK, BLK, 0, stream>>>(mn, 4*3*maps);
    int H = 16;
    for (int s = 0; s < 4; ++s){
      int Ho = 2*H;
      int tprR = (H >= 32) ? H/32 : 1;
      int tprO = Ho/32;
      int gR = nb*tprR*tprR;
      int gT = nb*tprO*tprO;
      int gM = nb*tprO*tprO;
      int g1 = gM, g2 = gM + gT;              // convm first, then convt, convr
      unsigned* mns = mn + (size_t)s*3*maps;
      conv3_fused<<<gM+gT+gR, BLK, 0, stream>>>(
          ws+o_X, ws+o_wr, ws+o_br, ws+o_wt, ws+o_bt, ws+o_wm, ws+o_bm,
          Db, Tb, Mb, mns, maps, H, b0, s, tprR, tprO, g1, g2);
      if (s < 3){
        long long totalq = (long long)maps*H*H;
        combine_kernel<<<grid_for(totalq), BLK, 0, stream>>>(
            Db, Tb, Mb, mns, maps, ws+o_X, H, (int)totalq);
      } else {
        long long totalf = (long long)nb*16384;
        combineF_kernel<<<grid_for(totalf), BLK, 0, stream>>>(
            Db, Tb, Mb, mns, maps, ws+o_wo, ws+o_bo, out, b0, (int)totalf);
      }
      H = Ho;
    }
  }
}